// Round 12
// baseline (1548.041 us; speedup 1.0000x reference)
//
#include <hip/hip_runtime.h>
#include <hip/hip_bf16.h>
#include <math.h>

// ---------------------------------------------------------------------------
// MultiLayerGAT: 3x GATConv (PyG-style, self-loops added) + log_softmax.
// N=10000, E=320000; 128->8x32(elu) -> 256->8x32(elu) -> 256->40 -> log_softmax
//
// R11: R10 megakernel with the barrier pathology fixed:
//   - spin poll uses RELAXED atomic load (no buffer_inv per poll; R10's
//     ACQUIRE-load-per-poll was an L1/L2 invalidate storm that starved the
//     whole chip), s_sleep(32) between polls, ONE acquire fence on exit.
//   - NB=2048, __launch_bounds__(256,8): 8 blocks/CU (52 VGPR < 64) -> full
//     32 waves/CU occupancy for the latency-bound aggregation phases.
// Phases identical to R10 (P0 prep/zero, P1 scatter||GEMM1, P2 agg1, P3 GEMM2,
// P4 agg2, P5 GEMM3, P6 agg_out). Numerics unchanged.
// ---------------------------------------------------------------------------

#define DEV_INLINE __device__ __forceinline__

typedef __attribute__((ext_vector_type(8))) short short8;
typedef __attribute__((ext_vector_type(4))) float f32x4;
typedef unsigned short ushort_t;
typedef unsigned int uint_t;

#define ELLW 128
#define NB 2048   // persistent grid: 256 CU x 8 blocks/CU (launch_bounds-guaranteed)

DEV_INLINE float leaky02(float x) { return x > 0.f ? x : 0.2f * x; }
DEV_INLINE float elu1(float x) { return x > 0.f ? x : expm1f(x); }

DEV_INLINE ushort_t f2bf(float f) {
    uint_t u = __float_as_uint(f);
    u += 0x7FFFu + ((u >> 16) & 1u);
    return (ushort_t)(u >> 16);
}
DEV_INLINE float bf2f(ushort_t u) { return __uint_as_float(((uint_t)u) << 16); }

// ---------------- grid barrier (monotonic counter, quiet polling) ------------

DEV_INLINE void gsync(int* bar, int phase) {
    __syncthreads();
    if (threadIdx.x == 0) {
        __threadfence();   // release: writeback this XCD's dirty lines
        __hip_atomic_fetch_add(bar, 1, __ATOMIC_RELAXED, __HIP_MEMORY_SCOPE_AGENT);
        // RELAXED poll: coherent load, NO cache-invalidate per iteration
        while (__hip_atomic_load(bar, __ATOMIC_RELAXED, __HIP_MEMORY_SCOPE_AGENT) < NB * phase) {
            __builtin_amdgcn_s_sleep(32);
        }
        __threadfence();   // acquire ONCE: invalidate stale lines for next phase
    }
    __syncthreads();
}

// ---------------- prep body: casts, transposes, al-weight folds --------------

DEV_INLINE void prep_body(int i,
                          const float* __restrict__ x, ushort_t* __restrict__ x_bf,
                          const float* __restrict__ W1, ushort_t* __restrict__ W1T,
                          const float* __restrict__ W2, ushort_t* __restrict__ W2T,
                          const float* __restrict__ W3, ushort_t* __restrict__ W3T,
                          const float* __restrict__ as1, const float* __restrict__ ad1,
                          const float* __restrict__ as2, const float* __restrict__ ad2,
                          const float* __restrict__ as3, const float* __restrict__ ad3,
                          int n) {
    int xcnt = n * 32;
    if (i < xcnt) {
        float4 v = *(const float4*)(x + (size_t)i * 4);
        ushort4 o;
        o.x = f2bf(v.x); o.y = f2bf(v.y); o.z = f2bf(v.z); o.w = f2bf(v.w);
        *(ushort4*)(x_bf + (size_t)i * 4) = o;
        return;
    }
    i -= xcnt;
    if (i < 128 * 256) {
        int k = i >> 8, c = i & 255;
        W1T[(size_t)c * 128 + k] = f2bf(W1[i]);
        return;
    }
    i -= 128 * 256;
    if (i < 256 * 256) {
        int k = i >> 8, c = i & 255;
        W2T[(size_t)c * 256 + k] = f2bf(W2[i]);
        return;
    }
    i -= 256 * 256;
    if (i < 256 * 40) {
        int k = i / 40, c = i - k * 40;
        W3T[(size_t)c * 256 + k] = f2bf(W3[i]);
        return;
    }
    i -= 256 * 40;
    if (i < 1024) {
        int h = i >> 7, k = i & 127;
        float acc = 0.f;
#pragma unroll
        for (int c = 0; c < 32; ++c) acc += W1[k * 256 + h * 32 + c] * as1[h * 32 + c];
        W1T[(size_t)(256 + h) * 128 + k] = f2bf(acc);
        return;
    }
    i -= 1024;
    if (i < 1024) {
        int h = i >> 7, k = i & 127;
        float acc = 0.f;
#pragma unroll
        for (int c = 0; c < 32; ++c) acc += W1[k * 256 + h * 32 + c] * ad1[h * 32 + c];
        W1T[(size_t)(264 + h) * 128 + k] = f2bf(acc);
        return;
    }
    i -= 1024;
    if (i < 2048) {
        int h = i >> 8, k = i & 255;
        float acc = 0.f;
#pragma unroll
        for (int c = 0; c < 32; ++c) acc += W2[k * 256 + h * 32 + c] * as2[h * 32 + c];
        W2T[(size_t)(256 + h) * 256 + k] = f2bf(acc);
        return;
    }
    i -= 2048;
    if (i < 2048) {
        int h = i >> 8, k = i & 255;
        float acc = 0.f;
#pragma unroll
        for (int c = 0; c < 32; ++c) acc += W2[k * 256 + h * 32 + c] * ad2[h * 32 + c];
        W2T[(size_t)(264 + h) * 256 + k] = f2bf(acc);
        return;
    }
    i -= 2048;
    if (i < 256) {
        float acc = 0.f;
#pragma unroll
        for (int c = 0; c < 40; ++c) acc += W3[i * 40 + c] * as3[c];
        W3T[(size_t)40 * 256 + i] = f2bf(acc);
        return;
    }
    i -= 256;
    if (i < 256) {
        float acc = 0.f;
#pragma unroll
        for (int c = 0; c < 40; ++c) acc += W3[i * 40 + c] * ad3[c];
        W3T[(size_t)41 * 256 + i] = f2bf(acc);
        return;
    }
}

// ---------------- ELL scatter body (one virtual block) -----------------------

DEV_INLINE void scatter_body(int vb, const int* __restrict__ src, const int* __restrict__ dst,
                             int* __restrict__ cursor, int* __restrict__ ell, int e) {
    int i4 = (vb * 256 + threadIdx.x) * 4;
    if (i4 + 3 < e) {
        int4 d = *(const int4*)(dst + i4);
        int4 s = *(const int4*)(src + i4);
        int p;
        p = atomicAdd(&cursor[d.x], 1); ell[d.x * ELLW + p] = s.x;
        p = atomicAdd(&cursor[d.y], 1); ell[d.y * ELLW + p] = s.y;
        p = atomicAdd(&cursor[d.z], 1); ell[d.z * ELLW + p] = s.z;
        p = atomicAdd(&cursor[d.w], 1); ell[d.w * ELLW + p] = s.w;
    } else {
        for (int k = i4; k < e; ++k) {
            int p = atomicAdd(&cursor[dst[k]], 1);
            ell[dst[k] * ELLW + p] = src[k];
        }
    }
}

// ---------------- MFMA GEMM body (cols >= NOUT routed to f32 als/ald) --------

DEV_INLINE int lds_slot(int r, int c) { return r * 4 + ((c + (r >> 1)) & 3); }

DEV_INLINE void gemm_body(ushort_t* __restrict__ As, ushort_t* __restrict__ Bs,
                          const ushort_t* __restrict__ A, const ushort_t* __restrict__ BT,
                          ushort_t* __restrict__ C, float* __restrict__ ALS,
                          float* __restrict__ ALD, int M, int NOUT, int NH, int NTOT,
                          int K, int bx, int by) {
    const int tid = threadIdx.x;
    const int wave = tid >> 6, lane = tid & 63;
    const int row0 = by * 64;
    const int col0 = bx * 64;

    const int sr = tid >> 2, sc = tid & 3;
    const int a_row = row0 + sr;
    const int b_row = col0 + sr;

    const int fr = lane & 15;
    const int fc = lane >> 4;

    f32x4 acc0 = {}, acc1 = {}, acc2 = {}, acc3 = {};

    for (int k0 = 0; k0 < K; k0 += 32) {
        short8 av = {}, bv = {};
        if (a_row < M) av = *(const short8*)(A + (size_t)a_row * K + k0 + sc * 8);
        if (b_row < NTOT) bv = *(const short8*)(BT + (size_t)b_row * K + k0 + sc * 8);
        __syncthreads();
        *(short8*)(As + lds_slot(sr, sc) * 8) = av;
        *(short8*)(Bs + lds_slot(sr, sc) * 8) = bv;
        __syncthreads();

        const int arow = wave * 16 + fr;
        short8 afrag = *(const short8*)(As + lds_slot(arow, fc) * 8);
        short8 b0 = *(const short8*)(Bs + lds_slot(0 * 16 + fr, fc) * 8);
        short8 b1 = *(const short8*)(Bs + lds_slot(1 * 16 + fr, fc) * 8);
        short8 b2 = *(const short8*)(Bs + lds_slot(2 * 16 + fr, fc) * 8);
        short8 b3 = *(const short8*)(Bs + lds_slot(3 * 16 + fr, fc) * 8);
        acc0 = __builtin_amdgcn_mfma_f32_16x16x32_bf16(afrag, b0, acc0, 0, 0, 0);
        acc1 = __builtin_amdgcn_mfma_f32_16x16x32_bf16(afrag, b1, acc1, 0, 0, 0);
        acc2 = __builtin_amdgcn_mfma_f32_16x16x32_bf16(afrag, b2, acc2, 0, 0, 0);
        acc3 = __builtin_amdgcn_mfma_f32_16x16x32_bf16(afrag, b3, acc3, 0, 0, 0);
    }
    __syncthreads();   // protect LDS reuse across grid-stride iterations

    const int crow = row0 + wave * 16 + (lane >> 4) * 4;
    const int ccol = col0 + (lane & 15);
    f32x4 accs[4] = {acc0, acc1, acc2, acc3};
#pragma unroll
    for (int ct = 0; ct < 4; ++ct) {
        int col = ccol + ct * 16;
#pragma unroll
        for (int j = 0; j < 4; ++j) {
            int row = crow + j;
            if (row >= M) continue;
            float v = accs[ct][j];
            if (col < NOUT) {
                C[(size_t)row * NOUT + col] = f2bf(v);
            } else {
                int cc = col - NOUT;
                if (cc < NH) ALS[(size_t)row * NH + cc] = v;
                else if (cc < 2 * NH) ALD[(size_t)row * NH + (cc - NH)] = v;
            }
        }
    }
}

// ---------------- aggregation node bodies (R9 inner loops) -------------------

DEV_INLINE void agg_h8_node(int node,
                            const ushort_t* __restrict__ xp, const float* __restrict__ als,
                            const float* __restrict__ ald, const int* __restrict__ degv,
                            const int* __restrict__ ell, const float* __restrict__ bias,
                            ushort_t* __restrict__ out) {
    const int lane = threadIdx.x & 63;
    const int half = lane >> 5;
    const int lh = lane & 31;
    const int ch = lh * 8;
    const int head = lh >> 2;
    const int deg = degv[node];
    const int rs = node * ELLW, re = rs + deg;
    const float ad = ald[node * 8 + head];
    const float m = leaky02(als[node * 8 + head] + ad);

    float acc[8];
    float ssum;
    if (half == 0) {
        short8 sv = *(const short8*)(xp + (size_t)node * 256 + ch);
#pragma unroll
        for (int i = 0; i < 8; ++i) acc[i] = bf2f((ushort_t)sv[i]);
        ssum = 1.0f;
    } else {
#pragma unroll
        for (int i = 0; i < 8; ++i) acc[i] = 0.f;
        ssum = 0.f;
    }

    for (int base = rs; base < re; base += 64) {
        const int cnt = (re - base < 64) ? (re - base) : 64;
        int myi = (lane < cnt) ? ell[base + lane] : 0;
        int j = 0;
        for (; j + 8 <= cnt; j += 8) {
            int s0 = __shfl(myi, j + half);
            int s1 = __shfl(myi, j + 2 + half);
            int s2 = __shfl(myi, j + 4 + half);
            int s3 = __shfl(myi, j + 6 + half);
            float a0 = als[s0 * 8 + head];
            float a1 = als[s1 * 8 + head];
            float a2 = als[s2 * 8 + head];
            float a3 = als[s3 * 8 + head];
            short8 v0 = *(const short8*)(xp + (size_t)s0 * 256 + ch);
            short8 v1 = *(const short8*)(xp + (size_t)s1 * 256 + ch);
            short8 v2 = *(const short8*)(xp + (size_t)s2 * 256 + ch);
            short8 v3 = *(const short8*)(xp + (size_t)s3 * 256 + ch);
            float p0 = __expf(leaky02(a0 + ad) - m);
            float p1 = __expf(leaky02(a1 + ad) - m);
            float p2 = __expf(leaky02(a2 + ad) - m);
            float p3 = __expf(leaky02(a3 + ad) - m);
            ssum += (p0 + p1) + (p2 + p3);
#pragma unroll
            for (int i = 0; i < 8; ++i)
                acc[i] += (p0 * bf2f((ushort_t)v0[i]) + p1 * bf2f((ushort_t)v1[i]))
                        + (p2 * bf2f((ushort_t)v2[i]) + p3 * bf2f((ushort_t)v3[i]));
        }
        for (; j < cnt; j += 2) {
            int jj = j + half;
            int s = __shfl(myi, jj & 63);
            bool valid = jj < cnt;
            float a = als[s * 8 + head];
            short8 v = *(const short8*)(xp + (size_t)s * 256 + ch);
            float p = valid ? __expf(leaky02(a + ad) - m) : 0.f;
            ssum += p;
#pragma unroll
            for (int i = 0; i < 8; ++i) acc[i] += p * bf2f((ushort_t)v[i]);
        }
    }

    ssum += __shfl_xor(ssum, 32);
#pragma unroll
    for (int i = 0; i < 8; ++i) acc[i] += __shfl_xor(acc[i], 32);

    if (half == 0) {
        float inv = 1.f / ssum;
        float4 ba = *(const float4*)(bias + ch);
        float4 bb = *(const float4*)(bias + ch + 4);
        float bv[8] = {ba.x, ba.y, ba.z, ba.w, bb.x, bb.y, bb.z, bb.w};
        short8 o;
#pragma unroll
        for (int i = 0; i < 8; ++i) o[i] = (short)f2bf(elu1(acc[i] * inv + bv[i]));
        *(short8*)(out + (size_t)node * 256 + ch) = o;
    }
}

DEV_INLINE void agg_out_node(int node,
                             const ushort_t* __restrict__ xp, const float* __restrict__ als,
                             const float* __restrict__ ald, const int* __restrict__ degv,
                             const int* __restrict__ ell, const float* __restrict__ bias,
                             float* __restrict__ out) {
    const int lane = threadIdx.x & 63;
    const int half = lane >> 5;
    const int lh = lane & 31;
    const bool act = lh < 20;
    const int ch = lh * 2;
    const int deg = degv[node];
    const int rs = node * ELLW, re = rs + deg;
    const float ad = ald[node];
    const float m = leaky02(als[node] + ad);

    float a0, a1, ssum;
    if (half == 0) {
        if (act) {
            ushort2 sv = *(const ushort2*)(xp + (size_t)node * 40 + ch);
            a0 = bf2f(sv.x); a1 = bf2f(sv.y);
        } else { a0 = a1 = 0.f; }
        ssum = 1.0f;
    } else { a0 = a1 = 0.f; ssum = 0.f; }

    for (int base = rs; base < re; base += 64) {
        const int cnt = (re - base < 64) ? (re - base) : 64;
        int myi = (lane < cnt) ? ell[base + lane] : 0;
        int j = 0;
        for (; j + 8 <= cnt; j += 8) {
            int s0 = __shfl(myi, j + half);
            int s1 = __shfl(myi, j + 2 + half);
            int s2 = __shfl(myi, j + 4 + half);
            int s3 = __shfl(myi, j + 6 + half);
            float e0 = als[s0];
            float e1 = als[s1];
            float e2 = als[s2];
            float e3 = als[s3];
            ushort2 v0 = act ? *(const ushort2*)(xp + (size_t)s0 * 40 + ch) : ushort2{0, 0};
            ushort2 v1 = act ? *(const ushort2*)(xp + (size_t)s1 * 40 + ch) : ushort2{0, 0};
            ushort2 v2 = act ? *(const ushort2*)(xp + (size_t)s2 * 40 + ch) : ushort2{0, 0};
            ushort2 v3 = act ? *(const ushort2*)(xp + (size_t)s3 * 40 + ch) : ushort2{0, 0};
            float p0 = __expf(leaky02(e0 + ad) - m);
            float p1 = __expf(leaky02(e1 + ad) - m);
            float p2 = __expf(leaky02(e2 + ad) - m);
            float p3 = __expf(leaky02(e3 + ad) - m);
            ssum += (p0 + p1) + (p2 + p3);
            a0 += (p0 * bf2f(v0.x) + p1 * bf2f(v1.x)) + (p2 * bf2f(v2.x) + p3 * bf2f(v3.x));
            a1 += (p0 * bf2f(v0.y) + p1 * bf2f(v1.y)) + (p2 * bf2f(v2.y) + p3 * bf2f(v3.y));
        }
        for (; j < cnt; j += 2) {
            int jj = j + half;
            int s = __shfl(myi, jj & 63);
            bool valid = jj < cnt;
            float a = als[s];
            ushort2 v = act ? *(const ushort2*)(xp + (size_t)s * 40 + ch) : ushort2{0, 0};
            float p = valid ? __expf(leaky02(a + ad) - m) : 0.f;
            ssum += p;
            a0 += p * bf2f(v.x);
            a1 += p * bf2f(v.y);
        }
    }

    ssum += __shfl_xor(ssum, 32);
    a0 += __shfl_xor(a0, 32);
    a1 += __shfl_xor(a1, 32);

    float inv = 1.f / ssum;
    float2 b2 = act ? *(const float2*)(bias + ch) : float2{0.f, 0.f};
    float o0 = act ? (a0 * inv + b2.x) : -INFINITY;
    float o1 = act ? (a1 * inv + b2.y) : -INFINITY;

    float mx = fmaxf(o0, o1);
#pragma unroll
    for (int off = 16; off >= 1; off >>= 1) mx = fmaxf(mx, __shfl_xor(mx, off));
    float ex = act ? (__expf(o0 - mx) + __expf(o1 - mx)) : 0.f;
#pragma unroll
    for (int off = 16; off >= 1; off >>= 1) ex += __shfl_xor(ex, off);
    float lse = mx + __logf(ex);
    if (half == 0 && act) {
        float2 o = {o0 - lse, o1 - lse};
        *(float2*)(out + (size_t)node * 40 + ch) = o;
    }
}

// ---------------- the megakernel ---------------------------------------------

__global__ __launch_bounds__(256, 8) void mega_kernel(
    const float* __restrict__ x, const int* __restrict__ edge,
    const float* __restrict__ W1, const float* __restrict__ as1,
    const float* __restrict__ ad1, const float* __restrict__ b1,
    const float* __restrict__ W2, const float* __restrict__ as2,
    const float* __restrict__ ad2, const float* __restrict__ b2,
    const float* __restrict__ W3, const float* __restrict__ as3,
    const float* __restrict__ ad3, const float* __restrict__ b3,
    float* __restrict__ out,
    ushort_t* __restrict__ xp, ushort_t* __restrict__ h_bf,
    ushort_t* __restrict__ xp3, ushort_t* __restrict__ x_bf,
    ushort_t* __restrict__ W1T, ushort_t* __restrict__ W2T, ushort_t* __restrict__ W3T,
    float* __restrict__ als, float* __restrict__ ald,
    int* __restrict__ cursor, int* __restrict__ ell, int* __restrict__ bar,
    int n, int e) {

    __shared__ ushort_t As[64 * 32];
    __shared__ ushort_t Bs[64 * 32];

    const int tid = threadIdx.x;
    const int bid = blockIdx.x;
    const int* srcs = edge;
    const int* dsts = edge + e;
    const int mby = (n + 63) / 64;                        // 157
    const int gw = (bid * 256 + tid) >> 6;                // global wave id
    const int nw = NB * 4;                                // total waves

    // ---- P0: zero cursor + prep ----
    {
        const int zvb = (n + 255) / 256;
        const int prep_total = n * 32 + 128 * 256 + 256 * 256 + 256 * 40
                             + 1024 + 1024 + 2048 + 2048 + 256 + 256;
        const int pvb = (prep_total + 255) / 256;
        for (int vb = bid; vb < zvb + pvb; vb += NB) {
            if (vb < zvb) {
                int i = vb * 256 + tid;
                if (i < n) cursor[i] = 0;
            } else {
                prep_body((vb - zvb) * 256 + tid, x, x_bf, W1, W1T, W2, W2T, W3, W3T,
                          as1, ad1, as2, ad2, as3, ad3, n);
            }
        }
    }
    gsync(bar, 1);

    // ---- P1: ELL scatter + layer-1 GEMM (independent) ----
    {
        const int svb = ((e + 3) / 4 + 255) / 256;
        const int gvb = 5 * mby;
        for (int vb = bid; vb < svb + gvb; vb += NB) {
            if (vb < svb) {
                scatter_body(vb, srcs, dsts, cursor, ell, e);
            } else {
                int t = vb - svb;
                gemm_body(As, Bs, x_bf, W1T, xp, als, ald, n, 256, 8, 272, 128, t % 5, t / 5);
            }
        }
    }
    gsync(bar, 2);

    // ---- P2: layer-1 aggregation ----
    for (int node = gw; node < n; node += nw)
        agg_h8_node(node, xp, als, ald, cursor, ell, b1, h_bf);
    gsync(bar, 3);

    // ---- P3: layer-2 GEMM ----
    for (int t = bid; t < 5 * mby; t += NB)
        gemm_body(As, Bs, h_bf, W2T, xp, als, ald, n, 256, 8, 272, 256, t % 5, t / 5);
    gsync(bar, 4);

    // ---- P4: layer-2 aggregation ----
    for (int node = gw; node < n; node += nw)
        agg_h8_node(node, xp, als, ald, cursor, ell, b2, h_bf);
    gsync(bar, 5);

    // ---- P5: layer-3 GEMM ----
    for (int t = bid; t < mby; t += NB)
        gemm_body(As, Bs, h_bf, W3T, xp3, als, ald, n, 40, 1, 42, 256, 0, t);
    gsync(bar, 6);

    // ---- P6: layer-3 aggregation + log_softmax ----
    for (int node = gw; node < n; node += nw)
        agg_out_node(node, xp3, als, ald, cursor, ell, b3, out);
}

// ---------------------------------------------------------------------------

extern "C" void kernel_launch(void* const* d_in, const int* in_sizes, int n_in,
                              void* d_out, int out_size, void* d_ws, size_t ws_size,
                              hipStream_t stream) {
    const float* x      = (const float*)d_in[0];
    const int*   edge   = (const int*)d_in[1];
    const float* W1     = (const float*)d_in[2];
    const float* a_src1 = (const float*)d_in[3];
    const float* a_dst1 = (const float*)d_in[4];
    const float* b1     = (const float*)d_in[5];
    const float* W2     = (const float*)d_in[6];
    const float* a_src2 = (const float*)d_in[7];
    const float* a_dst2 = (const float*)d_in[8];
    const float* b2     = (const float*)d_in[9];
    const float* W3     = (const float*)d_in[10];
    const float* a_src3 = (const float*)d_in[11];
    const float* a_dst3 = (const float*)d_in[12];
    const float* b3     = (const float*)d_in[13];
    float* out = (float*)d_out;

    const int n = in_sizes[0] / 128;   // 10000
    const int e = in_sizes[1] / 2;     // 320000

    char* ws = (char*)d_ws;
    size_t off = 0;
    auto alloc = [&](size_t bytes) -> void* {
        void* p = ws + off;
        off += (bytes + 255) & ~(size_t)255;
        return p;
    };
    ushort_t* xp        = (ushort_t*)alloc((size_t)n * 256 * 2);
    ushort_t* h_bf      = (ushort_t*)alloc((size_t)n * 256 * 2);
    ushort_t* xp3       = (ushort_t*)alloc((size_t)n * 40 * 2);
    ushort_t* x_bf      = (ushort_t*)alloc((size_t)n * 128 * 2);
    ushort_t* W1T       = (ushort_t*)alloc((size_t)272 * 128 * 2);
    ushort_t* W2T       = (ushort_t*)alloc((size_t)272 * 256 * 2);
    ushort_t* W3T       = (ushort_t*)alloc((size_t)42 * 256 * 2);
    float*    als       = (float*)alloc((size_t)n * 8 * 4);
    float*    ald       = (float*)alloc((size_t)n * 8 * 4);
    int*      cursor    = (int*)alloc((size_t)n * 4);
    int*      ell       = (int*)alloc((size_t)n * ELLW * 4);
    int*      bar       = (int*)alloc(256);
    (void)ws_size;

    // zero the barrier counter (cursor is zeroed inside P0)
    hipMemsetAsync(bar, 0, 256, stream);

    mega_kernel<<<NB, 256, 0, stream>>>(
        x, edge, W1, a_src1, a_dst1, b1, W2, a_src2, a_dst2, b2,
        W3, a_src3, a_dst3, b3, out,
        xp, h_bf, xp3, x_bf, W1T, W2T, W3T, als, ald, cursor, ell, bar, n, e);
}

// Round 14
// 106.016 us; speedup vs baseline: 14.6019x; 14.6019x over previous
//
#include <hip/hip_runtime.h>
#include <hip/hip_bf16.h>
#include <math.h>

// ---------------------------------------------------------------------------
// MultiLayerGAT: 3x GATConv (PyG-style, self-loops added) + log_softmax.
// N=10000, E=320000; 128->8x32(elu) -> 256->8x32(elu) -> 256->40 -> log_softmax
//
// R13 (revert-and-consolidate after megakernel line failed R10-R12):
// R9 structure with 3 trims:
//   - cursor-zero folded into prep (no memset dispatch)
//   - ELL scatter co-launched with layer-1 GEMM (independent after prep)
//   - GEMM1 stages A directly from f32 x (register cast) -> x_bf + 74% of
//     prep eliminated; scatter is 1 edge/thread (max atomic TLP).
// Pipeline: prep -> scatter||GEMM1 -> agg1 -> GEMM2 -> agg2 -> GEMM3 -> agg_out
// Aggregation / GEMM inner loops byte-identical to R9 (110us known-good).
// ---------------------------------------------------------------------------

#define DEV_INLINE __device__ __forceinline__

typedef __attribute__((ext_vector_type(8))) short short8;
typedef __attribute__((ext_vector_type(4))) float f32x4;
typedef unsigned short ushort_t;
typedef unsigned int uint_t;

#define ELLW 128

DEV_INLINE float leaky02(float x) { return x > 0.f ? x : 0.2f * x; }
DEV_INLINE float elu1(float x) { return x > 0.f ? x : expm1f(x); }

DEV_INLINE ushort_t f2bf(float f) {
    uint_t u = __float_as_uint(f);
    u += 0x7FFFu + ((u >> 16) & 1u);
    return (ushort_t)(u >> 16);
}
DEV_INLINE float bf2f(ushort_t u) { return __uint_as_float(((uint_t)u) << 16); }

// ---------------- prep: cursor zero + W transposes + al-weight folds ---------
// W1T_ext [272][128], W2T_ext [272][256], W3T_ext [42][256]:
//   rows 0..NOUT-1  : W^T (bf16)
//   rows NOUT..+NH-1: w_as[h][k] = sum_c W[k][h*C+c] * a_src[h][c]
//   rows +NH..+2NH-1: w_ad likewise

__global__ void prep_kernel(const float* __restrict__ W1, ushort_t* __restrict__ W1T,
                            const float* __restrict__ W2, ushort_t* __restrict__ W2T,
                            const float* __restrict__ W3, ushort_t* __restrict__ W3T,
                            const float* __restrict__ as1, const float* __restrict__ ad1,
                            const float* __restrict__ as2, const float* __restrict__ ad2,
                            const float* __restrict__ as3, const float* __restrict__ ad3,
                            int* __restrict__ cursor, int n) {
    int i = blockIdx.x * blockDim.x + threadIdx.x;
    if (i < n) { cursor[i] = 0; return; }
    i -= n;
    if (i < 128 * 256) {                       // W1 [128][256] -> rows 0..255
        int k = i >> 8, c = i & 255;
        W1T[(size_t)c * 128 + k] = f2bf(W1[i]);
        return;
    }
    i -= 128 * 256;
    if (i < 256 * 256) {                       // W2
        int k = i >> 8, c = i & 255;
        W2T[(size_t)c * 256 + k] = f2bf(W2[i]);
        return;
    }
    i -= 256 * 256;
    if (i < 256 * 40) {                        // W3 [256][40] -> rows 0..39
        int k = i / 40, c = i - k * 40;
        W3T[(size_t)c * 256 + k] = f2bf(W3[i]);
        return;
    }
    i -= 256 * 40;
    if (i < 1024) {                            // w_as1
        int h = i >> 7, k = i & 127;
        float acc = 0.f;
#pragma unroll
        for (int c = 0; c < 32; ++c) acc += W1[k * 256 + h * 32 + c] * as1[h * 32 + c];
        W1T[(size_t)(256 + h) * 128 + k] = f2bf(acc);
        return;
    }
    i -= 1024;
    if (i < 1024) {                            // w_ad1
        int h = i >> 7, k = i & 127;
        float acc = 0.f;
#pragma unroll
        for (int c = 0; c < 32; ++c) acc += W1[k * 256 + h * 32 + c] * ad1[h * 32 + c];
        W1T[(size_t)(264 + h) * 128 + k] = f2bf(acc);
        return;
    }
    i -= 1024;
    if (i < 2048) {                            // w_as2
        int h = i >> 8, k = i & 255;
        float acc = 0.f;
#pragma unroll
        for (int c = 0; c < 32; ++c) acc += W2[k * 256 + h * 32 + c] * as2[h * 32 + c];
        W2T[(size_t)(256 + h) * 256 + k] = f2bf(acc);
        return;
    }
    i -= 2048;
    if (i < 2048) {                            // w_ad2
        int h = i >> 8, k = i & 255;
        float acc = 0.f;
#pragma unroll
        for (int c = 0; c < 32; ++c) acc += W2[k * 256 + h * 32 + c] * ad2[h * 32 + c];
        W2T[(size_t)(264 + h) * 256 + k] = f2bf(acc);
        return;
    }
    i -= 2048;
    if (i < 256) {                             // w_as3
        float acc = 0.f;
#pragma unroll
        for (int c = 0; c < 40; ++c) acc += W3[i * 40 + c] * as3[c];
        W3T[(size_t)40 * 256 + i] = f2bf(acc);
        return;
    }
    i -= 256;
    if (i < 256) {                             // w_ad3
        float acc = 0.f;
#pragma unroll
        for (int c = 0; c < 40; ++c) acc += W3[i * 40 + c] * ad3[c];
        W3T[(size_t)41 * 256 + i] = f2bf(acc);
        return;
    }
}

// ---------------- MFMA GEMM bodies ------------------------------------------

DEV_INLINE int lds_slot(int r, int c) { return r * 4 + ((c + (r >> 1)) & 3); }

// generic bf16-A GEMM (cols >= NOUT routed to f32 als/ald)
DEV_INLINE void gemm_body(ushort_t* __restrict__ As, ushort_t* __restrict__ Bs,
                          const ushort_t* __restrict__ A, const ushort_t* __restrict__ BT,
                          ushort_t* __restrict__ C, float* __restrict__ ALS,
                          float* __restrict__ ALD, int M, int NOUT, int NH, int NTOT,
                          int K, int bx, int by) {
    const int tid = threadIdx.x;
    const int wave = tid >> 6, lane = tid & 63;
    const int row0 = by * 64;
    const int col0 = bx * 64;

    const int sr = tid >> 2, sc = tid & 3;
    const int a_row = row0 + sr;
    const int b_row = col0 + sr;

    const int fr = lane & 15;
    const int fc = lane >> 4;

    f32x4 acc0 = {}, acc1 = {}, acc2 = {}, acc3 = {};

    for (int k0 = 0; k0 < K; k0 += 32) {
        short8 av = {}, bv = {};
        if (a_row < M) av = *(const short8*)(A + (size_t)a_row * K + k0 + sc * 8);
        if (b_row < NTOT) bv = *(const short8*)(BT + (size_t)b_row * K + k0 + sc * 8);
        __syncthreads();
        *(short8*)(As + lds_slot(sr, sc) * 8) = av;
        *(short8*)(Bs + lds_slot(sr, sc) * 8) = bv;
        __syncthreads();

        const int arow = wave * 16 + fr;
        short8 afrag = *(const short8*)(As + lds_slot(arow, fc) * 8);
        short8 b0 = *(const short8*)(Bs + lds_slot(0 * 16 + fr, fc) * 8);
        short8 b1 = *(const short8*)(Bs + lds_slot(1 * 16 + fr, fc) * 8);
        short8 b2 = *(const short8*)(Bs + lds_slot(2 * 16 + fr, fc) * 8);
        short8 b3 = *(const short8*)(Bs + lds_slot(3 * 16 + fr, fc) * 8);
        acc0 = __builtin_amdgcn_mfma_f32_16x16x32_bf16(afrag, b0, acc0, 0, 0, 0);
        acc1 = __builtin_amdgcn_mfma_f32_16x16x32_bf16(afrag, b1, acc1, 0, 0, 0);
        acc2 = __builtin_amdgcn_mfma_f32_16x16x32_bf16(afrag, b2, acc2, 0, 0, 0);
        acc3 = __builtin_amdgcn_mfma_f32_16x16x32_bf16(afrag, b3, acc3, 0, 0, 0);
    }
    __syncthreads();

    const int crow = row0 + wave * 16 + (lane >> 4) * 4;
    const int ccol = col0 + (lane & 15);
    f32x4 accs[4] = {acc0, acc1, acc2, acc3};
#pragma unroll
    for (int ct = 0; ct < 4; ++ct) {
        int col = ccol + ct * 16;
#pragma unroll
        for (int j = 0; j < 4; ++j) {
            int row = crow + j;
            if (row >= M) continue;
            float v = accs[ct][j];
            if (col < NOUT) {
                C[(size_t)row * NOUT + col] = f2bf(v);
            } else {
                int cc = col - NOUT;
                if (cc < NH) ALS[(size_t)row * NH + cc] = v;
                else if (cc < 2 * NH) ALD[(size_t)row * NH + (cc - NH)] = v;
            }
        }
    }
}

// layer-1 GEMM: A staged directly from f32 x (cast in registers), K=128
DEV_INLINE void gemm1_body(ushort_t* __restrict__ As, ushort_t* __restrict__ Bs,
                           const float* __restrict__ X, const ushort_t* __restrict__ BT,
                           ushort_t* __restrict__ C, float* __restrict__ ALS,
                           float* __restrict__ ALD, int M, int bx, int by) {
    const int tid = threadIdx.x;
    const int wave = tid >> 6, lane = tid & 63;
    const int row0 = by * 64;
    const int col0 = bx * 64;

    const int sr = tid >> 2, sc = tid & 3;
    const int a_row = row0 + sr;
    const int b_row = col0 + sr;

    const int fr = lane & 15;
    const int fc = lane >> 4;

    f32x4 acc0 = {}, acc1 = {}, acc2 = {}, acc3 = {};

    for (int k0 = 0; k0 < 128; k0 += 32) {
        short8 av = {}, bv = {};
        if (a_row < M) {
            const float* xp = X + (size_t)a_row * 128 + k0 + sc * 8;
            float4 f0 = *(const float4*)(xp);
            float4 f1 = *(const float4*)(xp + 4);
            av[0] = (short)f2bf(f0.x); av[1] = (short)f2bf(f0.y);
            av[2] = (short)f2bf(f0.z); av[3] = (short)f2bf(f0.w);
            av[4] = (short)f2bf(f1.x); av[5] = (short)f2bf(f1.y);
            av[6] = (short)f2bf(f1.z); av[7] = (short)f2bf(f1.w);
        }
        if (b_row < 272) bv = *(const short8*)(BT + (size_t)b_row * 128 + k0 + sc * 8);
        __syncthreads();
        *(short8*)(As + lds_slot(sr, sc) * 8) = av;
        *(short8*)(Bs + lds_slot(sr, sc) * 8) = bv;
        __syncthreads();

        const int arow = wave * 16 + fr;
        short8 afrag = *(const short8*)(As + lds_slot(arow, fc) * 8);
        short8 b0 = *(const short8*)(Bs + lds_slot(0 * 16 + fr, fc) * 8);
        short8 b1 = *(const short8*)(Bs + lds_slot(1 * 16 + fr, fc) * 8);
        short8 b2 = *(const short8*)(Bs + lds_slot(2 * 16 + fr, fc) * 8);
        short8 b3 = *(const short8*)(Bs + lds_slot(3 * 16 + fr, fc) * 8);
        acc0 = __builtin_amdgcn_mfma_f32_16x16x32_bf16(afrag, b0, acc0, 0, 0, 0);
        acc1 = __builtin_amdgcn_mfma_f32_16x16x32_bf16(afrag, b1, acc1, 0, 0, 0);
        acc2 = __builtin_amdgcn_mfma_f32_16x16x32_bf16(afrag, b2, acc2, 0, 0, 0);
        acc3 = __builtin_amdgcn_mfma_f32_16x16x32_bf16(afrag, b3, acc3, 0, 0, 0);
    }
    __syncthreads();

    const int crow = row0 + wave * 16 + (lane >> 4) * 4;
    const int ccol = col0 + (lane & 15);
    f32x4 accs[4] = {acc0, acc1, acc2, acc3};
#pragma unroll
    for (int ct = 0; ct < 4; ++ct) {
        int col = ccol + ct * 16;
#pragma unroll
        for (int j = 0; j < 4; ++j) {
            int row = crow + j;
            if (row >= M) continue;
            float v = accs[ct][j];
            if (col < 256) {
                C[(size_t)row * 256 + col] = f2bf(v);
            } else {
                int cc = col - 256;
                if (cc < 8) ALS[(size_t)row * 8 + cc] = v;
                else if (cc < 16) ALD[(size_t)row * 8 + (cc - 8)] = v;
            }
        }
    }
}

__global__ __launch_bounds__(256) void gemm_kernel(const ushort_t* __restrict__ A,
                                                   const ushort_t* __restrict__ BT,
                                                   ushort_t* __restrict__ C,
                                                   float* __restrict__ ALS,
                                                   float* __restrict__ ALD,
                                                   int M, int NOUT, int NH, int NTOT,
                                                   int K, int gx) {
    __shared__ ushort_t As[64 * 32];
    __shared__ ushort_t Bs[64 * 32];
    gemm_body(As, Bs, A, BT, C, ALS, ALD, M, NOUT, NH, NTOT, K, blockIdx.x % gx, blockIdx.x / gx);
}

// blocks [0, svb): ELL scatter (1 edge/thread); blocks [svb, ..): layer-1 GEMM
__global__ __launch_bounds__(256) void scatter_gemm1_kernel(const int* __restrict__ src,
                                                            const int* __restrict__ dst,
                                                            int* __restrict__ cursor,
                                                            int* __restrict__ ell, int e,
                                                            int svb,
                                                            const float* __restrict__ X,
                                                            const ushort_t* __restrict__ BT,
                                                            ushort_t* __restrict__ C,
                                                            float* __restrict__ ALS,
                                                            float* __restrict__ ALD,
                                                            int M, int gx) {
    __shared__ ushort_t As[64 * 32];
    __shared__ ushort_t Bs[64 * 32];
    if (blockIdx.x < svb) {
        int i = blockIdx.x * 256 + threadIdx.x;
        if (i < e) {
            int d = dst[i];
            int p = atomicAdd(&cursor[d], 1);
            ell[d * ELLW + p] = src[i];
        }
        return;
    }
    int b = blockIdx.x - svb;
    gemm1_body(As, Bs, X, BT, C, ALS, ALD, M, b % gx, b / gx);
}

// ---------------- aggregation, layers 1-2: 1 wave/node, 8 edges/step ---------
// ELL row: edges at ell[node*ELLW + 0..deg). Half-waves own even/odd edges;
// depth-4 16B gathers. Cross-half combine via shfl_xor(32).

__global__ __launch_bounds__(256) void aggregate_h8_kernel(const ushort_t* __restrict__ xp,
                                                           const float* __restrict__ als,
                                                           const float* __restrict__ ald,
                                                           const int* __restrict__ degv,
                                                           const int* __restrict__ ell,
                                                           const float* __restrict__ bias,
                                                           ushort_t* __restrict__ out, int n) {
    int node = (blockIdx.x * blockDim.x + threadIdx.x) >> 6;
    int lane = threadIdx.x & 63;
    if (node >= n) return;
    const int half = lane >> 5;
    const int lh = lane & 31;
    const int ch = lh * 8;
    const int head = lh >> 2;
    const int deg = degv[node];
    const int rs = node * ELLW, re = rs + deg;
    const float ad = ald[node * 8 + head];
    const float m = leaky02(als[node * 8 + head] + ad);   // shift = self-loop logit

    float acc[8];
    float ssum;
    if (half == 0) {                       // self loop counted once
        short8 sv = *(const short8*)(xp + (size_t)node * 256 + ch);
#pragma unroll
        for (int i = 0; i < 8; ++i) acc[i] = bf2f((ushort_t)sv[i]);
        ssum = 1.0f;
    } else {
#pragma unroll
        for (int i = 0; i < 8; ++i) acc[i] = 0.f;
        ssum = 0.f;
    }

    for (int base = rs; base < re; base += 64) {
        const int cnt = (re - base < 64) ? (re - base) : 64;
        int myi = (lane < cnt) ? ell[base + lane] : 0;
        int j = 0;
        for (; j + 8 <= cnt; j += 8) {
            int s0 = __shfl(myi, j + half);
            int s1 = __shfl(myi, j + 2 + half);
            int s2 = __shfl(myi, j + 4 + half);
            int s3 = __shfl(myi, j + 6 + half);
            float a0 = als[s0 * 8 + head];
            float a1 = als[s1 * 8 + head];
            float a2 = als[s2 * 8 + head];
            float a3 = als[s3 * 8 + head];
            short8 v0 = *(const short8*)(xp + (size_t)s0 * 256 + ch);
            short8 v1 = *(const short8*)(xp + (size_t)s1 * 256 + ch);
            short8 v2 = *(const short8*)(xp + (size_t)s2 * 256 + ch);
            short8 v3 = *(const short8*)(xp + (size_t)s3 * 256 + ch);
            float p0 = __expf(leaky02(a0 + ad) - m);
            float p1 = __expf(leaky02(a1 + ad) - m);
            float p2 = __expf(leaky02(a2 + ad) - m);
            float p3 = __expf(leaky02(a3 + ad) - m);
            ssum += (p0 + p1) + (p2 + p3);
#pragma unroll
            for (int i = 0; i < 8; ++i)
                acc[i] += (p0 * bf2f((ushort_t)v0[i]) + p1 * bf2f((ushort_t)v1[i]))
                        + (p2 * bf2f((ushort_t)v2[i]) + p3 * bf2f((ushort_t)v3[i]));
        }
        for (; j < cnt; j += 2) {
            int jj = j + half;
            int s = __shfl(myi, jj & 63);
            bool valid = jj < cnt;
            float a = als[s * 8 + head];
            short8 v = *(const short8*)(xp + (size_t)s * 256 + ch);
            float p = valid ? __expf(leaky02(a + ad) - m) : 0.f;
            ssum += p;
#pragma unroll
            for (int i = 0; i < 8; ++i) acc[i] += p * bf2f((ushort_t)v[i]);
        }
    }

    ssum += __shfl_xor(ssum, 32);
#pragma unroll
    for (int i = 0; i < 8; ++i) acc[i] += __shfl_xor(acc[i], 32);

    if (half == 0) {
        float inv = 1.f / ssum;
        float4 ba = *(const float4*)(bias + ch);
        float4 bb = *(const float4*)(bias + ch + 4);
        float bv[8] = {ba.x, ba.y, ba.z, ba.w, bb.x, bb.y, bb.z, bb.w};
        short8 o;
#pragma unroll
        for (int i = 0; i < 8; ++i) o[i] = (short)f2bf(elu1(acc[i] * inv + bv[i]));
        *(short8*)(out + (size_t)node * 256 + ch) = o;
    }
}

// ---------------- aggregation layer 3 (H=1, C=40) + bias + log_softmax -------

__global__ __launch_bounds__(256) void aggregate_out_kernel(const ushort_t* __restrict__ xp,
                                                            const float* __restrict__ als,
                                                            const float* __restrict__ ald,
                                                            const int* __restrict__ degv,
                                                            const int* __restrict__ ell,
                                                            const float* __restrict__ bias,
                                                            float* __restrict__ out, int n) {
    int node = (blockIdx.x * blockDim.x + threadIdx.x) >> 6;
    int lane = threadIdx.x & 63;
    if (node >= n) return;
    const int half = lane >> 5;
    const int lh = lane & 31;
    const bool act = lh < 20;
    const int ch = lh * 2;
    const int deg = degv[node];
    const int rs = node * ELLW, re = rs + deg;
    const float ad = ald[node];
    const float m = leaky02(als[node] + ad);

    float a0, a1, ssum;
    if (half == 0) {
        if (act) {
            ushort2 sv = *(const ushort2*)(xp + (size_t)node * 40 + ch);
            a0 = bf2f(sv.x); a1 = bf2f(sv.y);
        } else { a0 = a1 = 0.f; }
        ssum = 1.0f;
    } else { a0 = a1 = 0.f; ssum = 0.f; }

    for (int base = rs; base < re; base += 64) {
        const int cnt = (re - base < 64) ? (re - base) : 64;
        int myi = (lane < cnt) ? ell[base + lane] : 0;
        int j = 0;
        for (; j + 8 <= cnt; j += 8) {
            int s0 = __shfl(myi, j + half);
            int s1 = __shfl(myi, j + 2 + half);
            int s2 = __shfl(myi, j + 4 + half);
            int s3 = __shfl(myi, j + 6 + half);
            float e0 = als[s0];
            float e1 = als[s1];
            float e2 = als[s2];
            float e3 = als[s3];
            ushort2 v0 = act ? *(const ushort2*)(xp + (size_t)s0 * 40 + ch) : ushort2{0, 0};
            ushort2 v1 = act ? *(const ushort2*)(xp + (size_t)s1 * 40 + ch) : ushort2{0, 0};
            ushort2 v2 = act ? *(const ushort2*)(xp + (size_t)s2 * 40 + ch) : ushort2{0, 0};
            ushort2 v3 = act ? *(const ushort2*)(xp + (size_t)s3 * 40 + ch) : ushort2{0, 0};
            float p0 = __expf(leaky02(e0 + ad) - m);
            float p1 = __expf(leaky02(e1 + ad) - m);
            float p2 = __expf(leaky02(e2 + ad) - m);
            float p3 = __expf(leaky02(e3 + ad) - m);
            ssum += (p0 + p1) + (p2 + p3);
            a0 += (p0 * bf2f(v0.x) + p1 * bf2f(v1.x)) + (p2 * bf2f(v2.x) + p3 * bf2f(v3.x));
            a1 += (p0 * bf2f(v0.y) + p1 * bf2f(v1.y)) + (p2 * bf2f(v2.y) + p3 * bf2f(v3.y));
        }
        for (; j < cnt; j += 2) {
            int jj = j + half;
            int s = __shfl(myi, jj & 63);
            bool valid = jj < cnt;
            float a = als[s];
            ushort2 v = act ? *(const ushort2*)(xp + (size_t)s * 40 + ch) : ushort2{0, 0};
            float p = valid ? __expf(leaky02(a + ad) - m) : 0.f;
            ssum += p;
            a0 += p * bf2f(v.x);
            a1 += p * bf2f(v.y);
        }
    }

    ssum += __shfl_xor(ssum, 32);
    a0 += __shfl_xor(a0, 32);
    a1 += __shfl_xor(a1, 32);

    float inv = 1.f / ssum;
    float2 b2 = act ? *(const float2*)(bias + ch) : float2{0.f, 0.f};
    float o0 = act ? (a0 * inv + b2.x) : -INFINITY;
    float o1 = act ? (a1 * inv + b2.y) : -INFINITY;

    float mx = fmaxf(o0, o1);
#pragma unroll
    for (int off = 16; off >= 1; off >>= 1) mx = fmaxf(mx, __shfl_xor(mx, off));
    float ex = act ? (__expf(o0 - mx) + __expf(o1 - mx)) : 0.f;
#pragma unroll
    for (int off = 16; off >= 1; off >>= 1) ex += __shfl_xor(ex, off);
    float lse = mx + __logf(ex);
    if (half == 0 && act) {
        float2 o = {o0 - lse, o1 - lse};
        *(float2*)(out + (size_t)node * 40 + ch) = o;
    }
}

// ---------------------------------------------------------------------------

extern "C" void kernel_launch(void* const* d_in, const int* in_sizes, int n_in,
                              void* d_out, int out_size, void* d_ws, size_t ws_size,
                              hipStream_t stream) {
    const float* x      = (const float*)d_in[0];
    const int*   edge   = (const int*)d_in[1];
    const float* W1     = (const float*)d_in[2];
    const float* a_src1 = (const float*)d_in[3];
    const float* a_dst1 = (const float*)d_in[4];
    const float* b1     = (const float*)d_in[5];
    const float* W2     = (const float*)d_in[6];
    const float* a_src2 = (const float*)d_in[7];
    const float* a_dst2 = (const float*)d_in[8];
    const float* b2     = (const float*)d_in[9];
    const float* W3     = (const float*)d_in[10];
    const float* a_src3 = (const float*)d_in[11];
    const float* a_dst3 = (const float*)d_in[12];
    const float* b3     = (const float*)d_in[13];
    float* out = (float*)d_out;

    const int n = in_sizes[0] / 128;   // 10000
    const int e = in_sizes[1] / 2;     // 320000

    char* ws = (char*)d_ws;
    size_t off = 0;
    auto alloc = [&](size_t bytes) -> void* {
        void* p = ws + off;
        off += (bytes + 255) & ~(size_t)255;
        return p;
    };
    ushort_t* xp        = (ushort_t*)alloc((size_t)n * 256 * 2);
    ushort_t* h_bf      = (ushort_t*)alloc((size_t)n * 256 * 2);
    ushort_t* xp3       = (ushort_t*)alloc((size_t)n * 40 * 2);
    ushort_t* W1T       = (ushort_t*)alloc((size_t)272 * 128 * 2);
    ushort_t* W2T       = (ushort_t*)alloc((size_t)272 * 256 * 2);
    ushort_t* W3T       = (ushort_t*)alloc((size_t)42 * 256 * 2);
    float*    als       = (float*)alloc((size_t)n * 8 * 4);
    float*    ald       = (float*)alloc((size_t)n * 8 * 4);
    int*      cursor    = (int*)alloc((size_t)n * 4);
    int*      ell       = (int*)alloc((size_t)n * ELLW * 4);
    (void)ws_size;

    const int* srcs = edge;
    const int* dsts = edge + e;

    const int mby = (n + 63) / 64;             // 157
    const int svb = (e + 255) / 256;           // 1250 scatter blocks (1 edge/thread)

    // K1: prep (cursor zero + W transposes + al folds)
    {
        int prep_total = n + 128 * 256 + 256 * 256 + 256 * 40
                       + 1024 + 1024 + 2048 + 2048 + 256 + 256;
        prep_kernel<<<(prep_total + 255) / 256, 256, 0, stream>>>(
            W1, W1T, W2, W2T, W3, W3T,
            a_src1, a_dst1, a_src2, a_dst2, a_src3, a_dst3, cursor, n);
    }
    // K2: ELL scatter || layer-1 GEMM (independent after prep)
    scatter_gemm1_kernel<<<svb + 5 * mby, 256, 0, stream>>>(
        srcs, dsts, cursor, ell, e, svb, x, W1T, xp, als, ald, n, 5);

    const int agg_grid = (n * 64 + 255) / 256;

    // K3: layer-1 aggregation (+bias+ELU) -> h_bf
    aggregate_h8_kernel<<<agg_grid, 256, 0, stream>>>(xp, als, ald, cursor, ell, b1, h_bf, n);
    // K4: layer-2 GEMM (+al fold)
    gemm_kernel<<<5 * mby, 256, 0, stream>>>(h_bf, W2T, xp, als, ald, n, 256, 8, 272, 256, 5);
    // K5: layer-2 aggregation -> h_bf
    aggregate_h8_kernel<<<agg_grid, 256, 0, stream>>>(xp, als, ald, cursor, ell, b2, h_bf, n);
    // K6: layer-3 GEMM (+al fold)
    gemm_kernel<<<1 * mby, 256, 0, stream>>>(h_bf, W3T, xp3, als, ald, n, 40, 1, 42, 256, 1);
    // K7: layer-3 aggregation + bias + log_softmax
    aggregate_out_kernel<<<agg_grid, 256, 0, stream>>>(xp3, als, ald, cursor, ell, b3, out, n);
}

// Round 15
// 101.854 us; speedup vs baseline: 15.1986x; 1.0409x over previous
//
#include <hip/hip_runtime.h>
#include <hip/hip_bf16.h>
#include <math.h>

// ---------------------------------------------------------------------------
// MultiLayerGAT: 3x GATConv (PyG-style, self-loops added) + log_softmax.
// N=10000, E=320000; 128->8x32(elu) -> 256->8x32(elu) -> 256->40 -> log_softmax
//
// R14 = R13 + fp8(e4m3) gathered features for layers 1-2:
//   - GEMM1/GEMM2 emit feature cols as OCP e4m3 (xp8, 1B/ch); al-logit cols
//     stay f32; h (agg output, GEMM A operand) stays bf16; xp3 stays bf16.
//   - aggregation gathers 8B/lane uint2 + v_cvt_pk_f32_fp8 decode (manual
//     fallback gated on __has_builtin). Halves dominant gather traffic.
// Pipeline unchanged: prep -> scatter||GEMM1 -> agg1 -> GEMM2 -> agg2 ->
// GEMM3 -> agg_out (7 dispatches).
// ---------------------------------------------------------------------------

#define DEV_INLINE __device__ __forceinline__

typedef __attribute__((ext_vector_type(8))) short short8;
typedef __attribute__((ext_vector_type(4))) float f32x4;
typedef __attribute__((ext_vector_type(2))) float f32x2;
typedef unsigned short ushort_t;
typedef unsigned int uint_t;
typedef unsigned char uchar_t;

#define ELLW 128

#if defined(__has_builtin)
#if __has_builtin(__builtin_amdgcn_cvt_pk_f32_fp8) && __has_builtin(__builtin_amdgcn_cvt_pk_fp8_f32)
#define FP8_HW 1
#endif
#endif
#ifndef FP8_HW
#define FP8_HW 0
#endif

DEV_INLINE float leaky02(float x) { return x > 0.f ? x : 0.2f * x; }
DEV_INLINE float elu1(float x) { return x > 0.f ? x : expm1f(x); }

DEV_INLINE ushort_t f2bf(float f) {
    uint_t u = __float_as_uint(f);
    u += 0x7FFFu + ((u >> 16) & 1u);
    return (ushort_t)(u >> 16);
}
DEV_INLINE float bf2f(ushort_t u) { return __uint_as_float(((uint_t)u) << 16); }

// ---- fp8 e4m3 (OCP) encode/decode ----

DEV_INLINE uint_t f2fp8(float v) {
#if FP8_HW
    return __builtin_amdgcn_cvt_pk_fp8_f32(v, v, 0, false) & 0xFFu;
#else
    float a = fabsf(v);
    uint_t s = (__float_as_uint(v) >> 24) & 0x80u;
    if (!(a >= 0.0009765625f)) return s;          // < 2^-10 -> +/-0
    if (a >= 448.f) return s | 0x7Eu;             // clamp to max finite
    if (a < 0.015625f) {                          // subnormal: m * 2^-9
        int m = (int)(a * 512.f + 0.5f);
        if (m >= 8) return s | 0x08u;
        return s | (uint_t)m;
    }
    uint_t ab = __float_as_uint(a);
    uint_t r = ab + 0x0007FFFFu + ((ab >> 20) & 1u);   // RNE to 3 mantissa bits
    uint_t e = (r >> 23) - 127u + 7u;
    uint_t m = (r >> 20) & 7u;
    if (e > 15u || (e == 15u && m == 7u)) return s | 0x7Eu;
    return s | (e << 3) | m;
#endif
}

DEV_INLINE void fp8x8_dec(uint2 w, float* f) {
#if FP8_HW
    f32x2 a0 = __builtin_amdgcn_cvt_pk_f32_fp8((int)w.x, false);
    f32x2 a1 = __builtin_amdgcn_cvt_pk_f32_fp8((int)w.x, true);
    f32x2 a2 = __builtin_amdgcn_cvt_pk_f32_fp8((int)w.y, false);
    f32x2 a3 = __builtin_amdgcn_cvt_pk_f32_fp8((int)w.y, true);
    f[0] = a0.x; f[1] = a0.y; f[2] = a1.x; f[3] = a1.y;
    f[4] = a2.x; f[5] = a2.y; f[6] = a3.x; f[7] = a3.y;
#else
    uint_t b[8] = {w.x & 255u, (w.x >> 8) & 255u, (w.x >> 16) & 255u, w.x >> 24,
                   w.y & 255u, (w.y >> 8) & 255u, (w.y >> 16) & 255u, w.y >> 24};
#pragma unroll
    for (int i = 0; i < 8; ++i) {
        uint_t em = b[i] & 0x7Fu;
        float mag = (em >= 8u) ? __uint_as_float(0x3C000000u + (em << 20))
                               : (float)(int)em * 0.001953125f;
        f[i] = (b[i] & 0x80u) ? -mag : mag;
    }
#endif
}

// ---------------- prep: cursor zero + W transposes + al-weight folds ---------

__global__ void prep_kernel(const float* __restrict__ W1, ushort_t* __restrict__ W1T,
                            const float* __restrict__ W2, ushort_t* __restrict__ W2T,
                            const float* __restrict__ W3, ushort_t* __restrict__ W3T,
                            const float* __restrict__ as1, const float* __restrict__ ad1,
                            const float* __restrict__ as2, const float* __restrict__ ad2,
                            const float* __restrict__ as3, const float* __restrict__ ad3,
                            int* __restrict__ cursor, int n) {
    int i = blockIdx.x * blockDim.x + threadIdx.x;
    if (i < n) { cursor[i] = 0; return; }
    i -= n;
    if (i < 128 * 256) {
        int k = i >> 8, c = i & 255;
        W1T[(size_t)c * 128 + k] = f2bf(W1[i]);
        return;
    }
    i -= 128 * 256;
    if (i < 256 * 256) {
        int k = i >> 8, c = i & 255;
        W2T[(size_t)c * 256 + k] = f2bf(W2[i]);
        return;
    }
    i -= 256 * 256;
    if (i < 256 * 40) {
        int k = i / 40, c = i - k * 40;
        W3T[(size_t)c * 256 + k] = f2bf(W3[i]);
        return;
    }
    i -= 256 * 40;
    if (i < 1024) {
        int h = i >> 7, k = i & 127;
        float acc = 0.f;
#pragma unroll
        for (int c = 0; c < 32; ++c) acc += W1[k * 256 + h * 32 + c] * as1[h * 32 + c];
        W1T[(size_t)(256 + h) * 128 + k] = f2bf(acc);
        return;
    }
    i -= 1024;
    if (i < 1024) {
        int h = i >> 7, k = i & 127;
        float acc = 0.f;
#pragma unroll
        for (int c = 0; c < 32; ++c) acc += W1[k * 256 + h * 32 + c] * ad1[h * 32 + c];
        W1T[(size_t)(264 + h) * 128 + k] = f2bf(acc);
        return;
    }
    i -= 1024;
    if (i < 2048) {
        int h = i >> 8, k = i & 255;
        float acc = 0.f;
#pragma unroll
        for (int c = 0; c < 32; ++c) acc += W2[k * 256 + h * 32 + c] * as2[h * 32 + c];
        W2T[(size_t)(256 + h) * 256 + k] = f2bf(acc);
        return;
    }
    i -= 2048;
    if (i < 2048) {
        int h = i >> 8, k = i & 255;
        float acc = 0.f;
#pragma unroll
        for (int c = 0; c < 32; ++c) acc += W2[k * 256 + h * 32 + c] * ad2[h * 32 + c];
        W2T[(size_t)(264 + h) * 256 + k] = f2bf(acc);
        return;
    }
    i -= 2048;
    if (i < 256) {
        float acc = 0.f;
#pragma unroll
        for (int c = 0; c < 40; ++c) acc += W3[i * 40 + c] * as3[c];
        W3T[(size_t)40 * 256 + i] = f2bf(acc);
        return;
    }
    i -= 256;
    if (i < 256) {
        float acc = 0.f;
#pragma unroll
        for (int c = 0; c < 40; ++c) acc += W3[i * 40 + c] * ad3[c];
        W3T[(size_t)41 * 256 + i] = f2bf(acc);
        return;
    }
}

// ---------------- MFMA GEMM bodies ------------------------------------------

DEV_INLINE int lds_slot(int r, int c) { return r * 4 + ((c + (r >> 1)) & 3); }

// generic bf16-A GEMM; feature cols -> fp8 (C8) or bf16 (Cbf); al cols -> f32
DEV_INLINE void gemm_body(ushort_t* __restrict__ As, ushort_t* __restrict__ Bs,
                          const ushort_t* __restrict__ A, const ushort_t* __restrict__ BT,
                          ushort_t* __restrict__ Cbf, uchar_t* __restrict__ C8,
                          float* __restrict__ ALS, float* __restrict__ ALD,
                          int M, int NOUT, int NH, int NTOT, int K, int bx, int by) {
    const int tid = threadIdx.x;
    const int wave = tid >> 6, lane = tid & 63;
    const int row0 = by * 64;
    const int col0 = bx * 64;

    const int sr = tid >> 2, sc = tid & 3;
    const int a_row = row0 + sr;
    const int b_row = col0 + sr;

    const int fr = lane & 15;
    const int fc = lane >> 4;

    f32x4 acc0 = {}, acc1 = {}, acc2 = {}, acc3 = {};

    for (int k0 = 0; k0 < K; k0 += 32) {
        short8 av = {}, bv = {};
        if (a_row < M) av = *(const short8*)(A + (size_t)a_row * K + k0 + sc * 8);
        if (b_row < NTOT) bv = *(const short8*)(BT + (size_t)b_row * K + k0 + sc * 8);
        __syncthreads();
        *(short8*)(As + lds_slot(sr, sc) * 8) = av;
        *(short8*)(Bs + lds_slot(sr, sc) * 8) = bv;
        __syncthreads();

        const int arow = wave * 16 + fr;
        short8 afrag = *(const short8*)(As + lds_slot(arow, fc) * 8);
        short8 b0 = *(const short8*)(Bs + lds_slot(0 * 16 + fr, fc) * 8);
        short8 b1 = *(const short8*)(Bs + lds_slot(1 * 16 + fr, fc) * 8);
        short8 b2 = *(const short8*)(Bs + lds_slot(2 * 16 + fr, fc) * 8);
        short8 b3 = *(const short8*)(Bs + lds_slot(3 * 16 + fr, fc) * 8);
        acc0 = __builtin_amdgcn_mfma_f32_16x16x32_bf16(afrag, b0, acc0, 0, 0, 0);
        acc1 = __builtin_amdgcn_mfma_f32_16x16x32_bf16(afrag, b1, acc1, 0, 0, 0);
        acc2 = __builtin_amdgcn_mfma_f32_16x16x32_bf16(afrag, b2, acc2, 0, 0, 0);
        acc3 = __builtin_amdgcn_mfma_f32_16x16x32_bf16(afrag, b3, acc3, 0, 0, 0);
    }
    __syncthreads();

    const int crow = row0 + wave * 16 + (lane >> 4) * 4;
    const int ccol = col0 + (lane & 15);
    f32x4 accs[4] = {acc0, acc1, acc2, acc3};
#pragma unroll
    for (int ct = 0; ct < 4; ++ct) {
        int col = ccol + ct * 16;
#pragma unroll
        for (int j = 0; j < 4; ++j) {
            int row = crow + j;
            if (row >= M) continue;
            float v = accs[ct][j];
            if (col < NOUT) {
                if (C8) C8[(size_t)row * NOUT + col] = (uchar_t)f2fp8(v);
                else    Cbf[(size_t)row * NOUT + col] = f2bf(v);
            } else {
                int cc = col - NOUT;
                if (cc < NH) ALS[(size_t)row * NH + cc] = v;
                else if (cc < 2 * NH) ALD[(size_t)row * NH + (cc - NH)] = v;
            }
        }
    }
}

// layer-1 GEMM: A staged directly from f32 x (register cast), K=128, fp8 out
DEV_INLINE void gemm1_body(ushort_t* __restrict__ As, ushort_t* __restrict__ Bs,
                           const float* __restrict__ X, const ushort_t* __restrict__ BT,
                           uchar_t* __restrict__ C8, float* __restrict__ ALS,
                           float* __restrict__ ALD, int M, int bx, int by) {
    const int tid = threadIdx.x;
    const int wave = tid >> 6, lane = tid & 63;
    const int row0 = by * 64;
    const int col0 = bx * 64;

    const int sr = tid >> 2, sc = tid & 3;
    const int a_row = row0 + sr;
    const int b_row = col0 + sr;

    const int fr = lane & 15;
    const int fc = lane >> 4;

    f32x4 acc0 = {}, acc1 = {}, acc2 = {}, acc3 = {};

    for (int k0 = 0; k0 < 128; k0 += 32) {
        short8 av = {}, bv = {};
        if (a_row < M) {
            const float* xp = X + (size_t)a_row * 128 + k0 + sc * 8;
            float4 f0 = *(const float4*)(xp);
            float4 f1 = *(const float4*)(xp + 4);
            av[0] = (short)f2bf(f0.x); av[1] = (short)f2bf(f0.y);
            av[2] = (short)f2bf(f0.z); av[3] = (short)f2bf(f0.w);
            av[4] = (short)f2bf(f1.x); av[5] = (short)f2bf(f1.y);
            av[6] = (short)f2bf(f1.z); av[7] = (short)f2bf(f1.w);
        }
        if (b_row < 272) bv = *(const short8*)(BT + (size_t)b_row * 128 + k0 + sc * 8);
        __syncthreads();
        *(short8*)(As + lds_slot(sr, sc) * 8) = av;
        *(short8*)(Bs + lds_slot(sr, sc) * 8) = bv;
        __syncthreads();

        const int arow = wave * 16 + fr;
        short8 afrag = *(const short8*)(As + lds_slot(arow, fc) * 8);
        short8 b0 = *(const short8*)(Bs + lds_slot(0 * 16 + fr, fc) * 8);
        short8 b1 = *(const short8*)(Bs + lds_slot(1 * 16 + fr, fc) * 8);
        short8 b2 = *(const short8*)(Bs + lds_slot(2 * 16 + fr, fc) * 8);
        short8 b3 = *(const short8*)(Bs + lds_slot(3 * 16 + fr, fc) * 8);
        acc0 = __builtin_amdgcn_mfma_f32_16x16x32_bf16(afrag, b0, acc0, 0, 0, 0);
        acc1 = __builtin_amdgcn_mfma_f32_16x16x32_bf16(afrag, b1, acc1, 0, 0, 0);
        acc2 = __builtin_amdgcn_mfma_f32_16x16x32_bf16(afrag, b2, acc2, 0, 0, 0);
        acc3 = __builtin_amdgcn_mfma_f32_16x16x32_bf16(afrag, b3, acc3, 0, 0, 0);
    }
    __syncthreads();

    const int crow = row0 + wave * 16 + (lane >> 4) * 4;
    const int ccol = col0 + (lane & 15);
    f32x4 accs[4] = {acc0, acc1, acc2, acc3};
#pragma unroll
    for (int ct = 0; ct < 4; ++ct) {
        int col = ccol + ct * 16;
#pragma unroll
        for (int j = 0; j < 4; ++j) {
            int row = crow + j;
            if (row >= M) continue;
            float v = accs[ct][j];
            if (col < 256) {
                C8[(size_t)row * 256 + col] = (uchar_t)f2fp8(v);
            } else {
                int cc = col - 256;
                if (cc < 8) ALS[(size_t)row * 8 + cc] = v;
                else if (cc < 16) ALD[(size_t)row * 8 + (cc - 8)] = v;
            }
        }
    }
}

__global__ __launch_bounds__(256) void gemm_kernel(const ushort_t* __restrict__ A,
                                                   const ushort_t* __restrict__ BT,
                                                   ushort_t* __restrict__ Cbf,
                                                   uchar_t* __restrict__ C8,
                                                   float* __restrict__ ALS,
                                                   float* __restrict__ ALD,
                                                   int M, int NOUT, int NH, int NTOT,
                                                   int K, int gx) {
    __shared__ ushort_t As[64 * 32];
    __shared__ ushort_t Bs[64 * 32];
    gemm_body(As, Bs, A, BT, Cbf, C8, ALS, ALD, M, NOUT, NH, NTOT, K,
              blockIdx.x % gx, blockIdx.x / gx);
}

// blocks [0, svb): ELL scatter (1 edge/thread); blocks [svb, ..): layer-1 GEMM
__global__ __launch_bounds__(256) void scatter_gemm1_kernel(const int* __restrict__ src,
                                                            const int* __restrict__ dst,
                                                            int* __restrict__ cursor,
                                                            int* __restrict__ ell, int e,
                                                            int svb,
                                                            const float* __restrict__ X,
                                                            const ushort_t* __restrict__ BT,
                                                            uchar_t* __restrict__ C8,
                                                            float* __restrict__ ALS,
                                                            float* __restrict__ ALD,
                                                            int M, int gx) {
    __shared__ ushort_t As[64 * 32];
    __shared__ ushort_t Bs[64 * 32];
    if (blockIdx.x < svb) {
        int i = blockIdx.x * 256 + threadIdx.x;
        if (i < e) {
            int d = dst[i];
            int p = atomicAdd(&cursor[d], 1);
            ell[d * ELLW + p] = src[i];
        }
        return;
    }
    int b = blockIdx.x - svb;
    gemm1_body(As, Bs, X, BT, C8, ALS, ALD, M, b % gx, b / gx);
}

// ---------------- aggregation, layers 1-2 (fp8 gathers) ----------------------
// ELL row: edges at ell[node*ELLW + 0..deg). Half-waves own even/odd edges;
// depth-4 8B uint2 gathers + fp8 decode. Cross-half combine via shfl_xor(32).

__global__ __launch_bounds__(256) void aggregate_h8_kernel(const uchar_t* __restrict__ xp8,
                                                           const float* __restrict__ als,
                                                           const float* __restrict__ ald,
                                                           const int* __restrict__ degv,
                                                           const int* __restrict__ ell,
                                                           const float* __restrict__ bias,
                                                           ushort_t* __restrict__ out, int n) {
    int node = (blockIdx.x * blockDim.x + threadIdx.x) >> 6;
    int lane = threadIdx.x & 63;
    if (node >= n) return;
    const int half = lane >> 5;
    const int lh = lane & 31;
    const int ch = lh * 8;                 // 8 channels (bytes) per lane
    const int head = lh >> 2;
    const int deg = degv[node];
    const int rs = node * ELLW, re = rs + deg;
    const float ad = ald[node * 8 + head];
    const float m = leaky02(als[node * 8 + head] + ad);   // shift = self-loop logit

    float acc[8];
    float ssum;
    if (half == 0) {                       // self loop counted once
        uint2 sv = *(const uint2*)(xp8 + (size_t)node * 256 + ch);
        float sf[8];
        fp8x8_dec(sv, sf);
#pragma unroll
        for (int i = 0; i < 8; ++i) acc[i] = sf[i];
        ssum = 1.0f;
    } else {
#pragma unroll
        for (int i = 0; i < 8; ++i) acc[i] = 0.f;
        ssum = 0.f;
    }

    for (int base = rs; base < re; base += 64) {
        const int cnt = (re - base < 64) ? (re - base) : 64;
        int myi = (lane < cnt) ? ell[base + lane] : 0;
        int j = 0;
        for (; j + 8 <= cnt; j += 8) {     // 8 edges: 4 per half, 4 loads in flight
            int s0 = __shfl(myi, j + half);
            int s1 = __shfl(myi, j + 2 + half);
            int s2 = __shfl(myi, j + 4 + half);
            int s3 = __shfl(myi, j + 6 + half);
            float a0 = als[s0 * 8 + head];
            float a1 = als[s1 * 8 + head];
            float a2 = als[s2 * 8 + head];
            float a3 = als[s3 * 8 + head];
            uint2 v0 = *(const uint2*)(xp8 + (size_t)s0 * 256 + ch);
            uint2 v1 = *(const uint2*)(xp8 + (size_t)s1 * 256 + ch);
            uint2 v2 = *(const uint2*)(xp8 + (size_t)s2 * 256 + ch);
            uint2 v3 = *(const uint2*)(xp8 + (size_t)s3 * 256 + ch);
            float p0 = __expf(leaky02(a0 + ad) - m);
            float p1 = __expf(leaky02(a1 + ad) - m);
            float p2 = __expf(leaky02(a2 + ad) - m);
            float p3 = __expf(leaky02(a3 + ad) - m);
            ssum += (p0 + p1) + (p2 + p3);
            float f0[8], f1[8], f2[8], f3[8];
            fp8x8_dec(v0, f0);
            fp8x8_dec(v1, f1);
            fp8x8_dec(v2, f2);
            fp8x8_dec(v3, f3);
#pragma unroll
            for (int i = 0; i < 8; ++i)
                acc[i] += (p0 * f0[i] + p1 * f1[i]) + (p2 * f2[i] + p3 * f3[i]);
        }
        for (; j < cnt; j += 2) {          // guarded tail
            int jj = j + half;
            int s = __shfl(myi, jj & 63);
            bool valid = jj < cnt;
            float a = als[s * 8 + head];
            uint2 v = *(const uint2*)(xp8 + (size_t)s * 256 + ch);
            float p = valid ? __expf(leaky02(a + ad) - m) : 0.f;
            ssum += p;
            float fv[8];
            fp8x8_dec(v, fv);
#pragma unroll
            for (int i = 0; i < 8; ++i) acc[i] += p * fv[i];
        }
    }

    ssum += __shfl_xor(ssum, 32);
#pragma unroll
    for (int i = 0; i < 8; ++i) acc[i] += __shfl_xor(acc[i], 32);

    if (half == 0) {
        float inv = 1.f / ssum;
        float4 ba = *(const float4*)(bias + ch);
        float4 bb = *(const float4*)(bias + ch + 4);
        float bv[8] = {ba.x, ba.y, ba.z, ba.w, bb.x, bb.y, bb.z, bb.w};
        short8 o;
#pragma unroll
        for (int i = 0; i < 8; ++i) o[i] = (short)f2bf(elu1(acc[i] * inv + bv[i]));
        *(short8*)(out + (size_t)node * 256 + ch) = o;
    }
}

// ---------------- aggregation layer 3 (H=1, C=40, bf16) + log_softmax --------

__global__ __launch_bounds__(256) void aggregate_out_kernel(const ushort_t* __restrict__ xp,
                                                            const float* __restrict__ als,
                                                            const float* __restrict__ ald,
                                                            const int* __restrict__ degv,
                                                            const int* __restrict__ ell,
                                                            const float* __restrict__ bias,
                                                            float* __restrict__ out, int n) {
    int node = (blockIdx.x * blockDim.x + threadIdx.x) >> 6;
    int lane = threadIdx.x & 63;
    if (node >= n) return;
    const int half = lane >> 5;
    const int lh = lane & 31;
    const bool act = lh < 20;
    const int ch = lh * 2;
    const int deg = degv[node];
    const int rs = node * ELLW, re = rs + deg;
    const float ad = ald[node];
    const float m = leaky02(als[node] + ad);

    float a0, a1, ssum;
    if (half == 0) {
        if (act) {
            ushort2 sv = *(const ushort2*)(xp + (size_t)node * 40 + ch);
            a0 = bf2f(sv.x); a1 = bf2f(sv.y);
        } else { a0 = a1 = 0.f; }
        ssum = 1.0f;
    } else { a0 = a1 = 0.f; ssum = 0.f; }

    for (int base = rs; base < re; base += 64) {
        const int cnt = (re - base < 64) ? (re - base) : 64;
        int myi = (lane < cnt) ? ell[base + lane] : 0;
        int j = 0;
        for (; j + 8 <= cnt; j += 8) {
            int s0 = __shfl(myi, j + half);
            int s1 = __shfl(myi, j + 2 + half);
            int s2 = __shfl(myi, j + 4 + half);
            int s3 = __shfl(myi, j + 6 + half);
            float e0 = als[s0];
            float e1 = als[s1];
            float e2 = als[s2];
            float e3 = als[s3];
            ushort2 v0 = act ? *(const ushort2*)(xp + (size_t)s0 * 40 + ch) : ushort2{0, 0};
            ushort2 v1 = act ? *(const ushort2*)(xp + (size_t)s1 * 40 + ch) : ushort2{0, 0};
            ushort2 v2 = act ? *(const ushort2*)(xp + (size_t)s2 * 40 + ch) : ushort2{0, 0};
            ushort2 v3 = act ? *(const ushort2*)(xp + (size_t)s3 * 40 + ch) : ushort2{0, 0};
            float p0 = __expf(leaky02(e0 + ad) - m);
            float p1 = __expf(leaky02(e1 + ad) - m);
            float p2 = __expf(leaky02(e2 + ad) - m);
            float p3 = __expf(leaky02(e3 + ad) - m);
            ssum += (p0 + p1) + (p2 + p3);
            a0 += (p0 * bf2f(v0.x) + p1 * bf2f(v1.x)) + (p2 * bf2f(v2.x) + p3 * bf2f(v3.x));
            a1 += (p0 * bf2f(v0.y) + p1 * bf2f(v1.y)) + (p2 * bf2f(v2.y) + p3 * bf2f(v3.y));
        }
        for (; j < cnt; j += 2) {
            int jj = j + half;
            int s = __shfl(myi, jj & 63);
            bool valid = jj < cnt;
            float a = als[s];
            ushort2 v = act ? *(const ushort2*)(xp + (size_t)s * 40 + ch) : ushort2{0, 0};
            float p = valid ? __expf(leaky02(a + ad) - m) : 0.f;
            ssum += p;
            a0 += p * bf2f(v.x);
            a1 += p * bf2f(v.y);
        }
    }

    ssum += __shfl_xor(ssum, 32);
    a0 += __shfl_xor(a0, 32);
    a1 += __shfl_xor(a1, 32);

    float inv = 1.f / ssum;
    float2 b2 = act ? *(const float2*)(bias + ch) : float2{0.f, 0.f};
    float o0 = act ? (a0 * inv + b2.x) : -INFINITY;
    float o1 = act ? (a1 * inv + b2.y) : -INFINITY;

    float mx = fmaxf(o0, o1);
#pragma unroll
    for (int off = 16; off >= 1; off >>= 1) mx = fmaxf(mx, __shfl_xor(mx, off));
    float ex = act ? (__expf(o0 - mx) + __expf(o1 - mx)) : 0.f;
#pragma unroll
    for (int off = 16; off >= 1; off >>= 1) ex += __shfl_xor(ex, off);
    float lse = mx + __logf(ex);
    if (half == 0 && act) {
        float2 o = {o0 - lse, o1 - lse};
        *(float2*)(out + (size_t)node * 40 + ch) = o;
    }
}

// ---------------------------------------------------------------------------

extern "C" void kernel_launch(void* const* d_in, const int* in_sizes, int n_in,
                              void* d_out, int out_size, void* d_ws, size_t ws_size,
                              hipStream_t stream) {
    const float* x      = (const float*)d_in[0];
    const int*   edge   = (const int*)d_in[1];
    const float* W1     = (const float*)d_in[2];
    const float* a_src1 = (const float*)d_in[3];
    const float* a_dst1 = (const float*)d_in[4];
    const float* b1     = (const float*)d_in[5];
    const float* W2     = (const float*)d_in[6];
    const float* a_src2 = (const float*)d_in[7];
    const float* a_dst2 = (const float*)d_in[8];
    const float* b2     = (const float*)d_in[9];
    const float* W3     = (const float*)d_in[10];
    const float* a_src3 = (const float*)d_in[11];
    const float* a_dst3 = (const float*)d_in[12];
    const float* b3     = (const float*)d_in[13];
    float* out = (float*)d_out;

    const int n = in_sizes[0] / 128;   // 10000
    const int e = in_sizes[1] / 2;     // 320000

    char* ws = (char*)d_ws;
    size_t off = 0;
    auto alloc = [&](size_t bytes) -> void* {
        void* p = ws + off;
        off += (bytes + 255) & ~(size_t)255;
        return p;
    };
    uchar_t*  xp8       = (uchar_t*)alloc((size_t)n * 256);       // fp8 features (L1/L2)
    ushort_t* h_bf      = (ushort_t*)alloc((size_t)n * 256 * 2);  // agg output (GEMM A)
    ushort_t* xp3       = (ushort_t*)alloc((size_t)n * 40 * 2);   // L3 features bf16
    ushort_t* W1T       = (ushort_t*)alloc((size_t)272 * 128 * 2);
    ushort_t* W2T       = (ushort_t*)alloc((size_t)272 * 256 * 2);
    ushort_t* W3T       = (ushort_t*)alloc((size_t)42 * 256 * 2);
    float*    als       = (float*)alloc((size_t)n * 8 * 4);
    float*    ald       = (float*)alloc((size_t)n * 8 * 4);
    int*      cursor    = (int*)alloc((size_t)n * 4);
    int*      ell       = (int*)alloc((size_t)n * ELLW * 4);
    (void)ws_size;

    const int* srcs = edge;
    const int* dsts = edge + e;

    const int mby = (n + 63) / 64;             // 157
    const int svb = (e + 255) / 256;           // scatter blocks (1 edge/thread)

    // K1: prep (cursor zero + W transposes + al folds)
    {
        int prep_total = n + 128 * 256 + 256 * 256 + 256 * 40
                       + 1024 + 1024 + 2048 + 2048 + 256 + 256;
        prep_kernel<<<(prep_total + 255) / 256, 256, 0, stream>>>(
            W1, W1T, W2, W2T, W3, W3T,
            a_src1, a_dst1, a_src2, a_dst2, a_src3, a_dst3, cursor, n);
    }
    // K2: ELL scatter || layer-1 GEMM (fp8 out)
    scatter_gemm1_kernel<<<svb + 5 * mby, 256, 0, stream>>>(
        srcs, dsts, cursor, ell, e, svb, x, W1T, xp8, als, ald, n, 5);

    const int agg_grid = (n * 64 + 255) / 256;

    // K3: layer-1 aggregation (+bias+ELU) -> h_bf
    aggregate_h8_kernel<<<agg_grid, 256, 0, stream>>>(xp8, als, ald, cursor, ell, b1, h_bf, n);
    // K4: layer-2 GEMM (fp8 out + al fold)
    gemm_kernel<<<5 * mby, 256, 0, stream>>>(h_bf, W2T, nullptr, xp8, als, ald,
                                             n, 256, 8, 272, 256, 5);
    // K5: layer-2 aggregation -> h_bf
    aggregate_h8_kernel<<<agg_grid, 256, 0, stream>>>(xp8, als, ald, cursor, ell, b2, h_bf, n);
    // K6: layer-3 GEMM (bf16 out + al fold)
    gemm_kernel<<<1 * mby, 256, 0, stream>>>(h_bf, W3T, xp3, nullptr, als, ald,
                                             n, 40, 1, 42, 256, 1);
    // K7: layer-3 aggregation + bias + log_softmax
    aggregate_out_kernel<<<agg_grid, 256, 0, stream>>>(xp3, als, ald, cursor, ell, b3, out, n);
}

// Round 16
// 101.486 us; speedup vs baseline: 15.2537x; 1.0036x over previous
//
#include <hip/hip_runtime.h>
#include <hip/hip_bf16.h>
#include <math.h>

// ---------------------------------------------------------------------------
// MultiLayerGAT: 3x GATConv (PyG-style, self-loops added) + log_softmax.
// N=10000, E=320000; 128->8x32(elu) -> 256->8x32(elu) -> 256->40 -> log_softmax
//
// R15 = R14 + GEMM3 fused into agg2's epilogue:
//   - after the cross-half combine, all 64 lanes hold h[node] (8 f32/lane);
//     the wave computes the 42 layer-3 columns (40 features + als3/ald3)
//     directly: 21 outputs/half x (8 FMA + 16B W3T slice + 5-shfl butterfly).
//   - kills the GEMM3 dispatch+boundary and the layer-3 h_bf materialization.
//   - layer-3 logits in separate als3/ald3 (no race with in-flight gathers).
// Pipeline: prep -> scatter||GEMM1 -> agg1 -> GEMM2 -> agg2+gemm3 -> agg_out
// (6 dispatches). fp8 gathered features as in R14.
// ---------------------------------------------------------------------------

#define DEV_INLINE __device__ __forceinline__

typedef __attribute__((ext_vector_type(8))) short short8;
typedef __attribute__((ext_vector_type(4))) float f32x4;
typedef __attribute__((ext_vector_type(2))) float f32x2;
typedef unsigned short ushort_t;
typedef unsigned int uint_t;
typedef unsigned char uchar_t;

#define ELLW 128

#if defined(__has_builtin)
#if __has_builtin(__builtin_amdgcn_cvt_pk_f32_fp8) && __has_builtin(__builtin_amdgcn_cvt_pk_fp8_f32)
#define FP8_HW 1
#endif
#endif
#ifndef FP8_HW
#define FP8_HW 0
#endif

DEV_INLINE float leaky02(float x) { return x > 0.f ? x : 0.2f * x; }
DEV_INLINE float elu1(float x) { return x > 0.f ? x : expm1f(x); }

DEV_INLINE ushort_t f2bf(float f) {
    uint_t u = __float_as_uint(f);
    u += 0x7FFFu + ((u >> 16) & 1u);
    return (ushort_t)(u >> 16);
}
DEV_INLINE float bf2f(ushort_t u) { return __uint_as_float(((uint_t)u) << 16); }

// ---- fp8 e4m3 (OCP) encode/decode ----

DEV_INLINE uint_t f2fp8(float v) {
#if FP8_HW
    return __builtin_amdgcn_cvt_pk_fp8_f32(v, v, 0, false) & 0xFFu;
#else
    float a = fabsf(v);
    uint_t s = (__float_as_uint(v) >> 24) & 0x80u;
    if (!(a >= 0.0009765625f)) return s;
    if (a >= 448.f) return s | 0x7Eu;
    if (a < 0.015625f) {
        int m = (int)(a * 512.f + 0.5f);
        if (m >= 8) return s | 0x08u;
        return s | (uint_t)m;
    }
    uint_t ab = __float_as_uint(a);
    uint_t r = ab + 0x0007FFFFu + ((ab >> 20) & 1u);
    uint_t e = (r >> 23) - 127u + 7u;
    uint_t m = (r >> 20) & 7u;
    if (e > 15u || (e == 15u && m == 7u)) return s | 0x7Eu;
    return s | (e << 3) | m;
#endif
}

DEV_INLINE void fp8x8_dec(uint2 w, float* f) {
#if FP8_HW
    f32x2 a0 = __builtin_amdgcn_cvt_pk_f32_fp8((int)w.x, false);
    f32x2 a1 = __builtin_amdgcn_cvt_pk_f32_fp8((int)w.x, true);
    f32x2 a2 = __builtin_amdgcn_cvt_pk_f32_fp8((int)w.y, false);
    f32x2 a3 = __builtin_amdgcn_cvt_pk_f32_fp8((int)w.y, true);
    f[0] = a0.x; f[1] = a0.y; f[2] = a1.x; f[3] = a1.y;
    f[4] = a2.x; f[5] = a2.y; f[6] = a3.x; f[7] = a3.y;
#else
    uint_t b[8] = {w.x & 255u, (w.x >> 8) & 255u, (w.x >> 16) & 255u, w.x >> 24,
                   w.y & 255u, (w.y >> 8) & 255u, (w.y >> 16) & 255u, w.y >> 24};
#pragma unroll
    for (int i = 0; i < 8; ++i) {
        uint_t em = b[i] & 0x7Fu;
        float mag = (em >= 8u) ? __uint_as_float(0x3C000000u + (em << 20))
                               : (float)(int)em * 0.001953125f;
        f[i] = (b[i] & 0x80u) ? -mag : mag;
    }
#endif
}

// ---------------- prep: cursor zero + W transposes + al-weight folds ---------

__global__ void prep_kernel(const float* __restrict__ W1, ushort_t* __restrict__ W1T,
                            const float* __restrict__ W2, ushort_t* __restrict__ W2T,
                            const float* __restrict__ W3, ushort_t* __restrict__ W3T,
                            const float* __restrict__ as1, const float* __restrict__ ad1,
                            const float* __restrict__ as2, const float* __restrict__ ad2,
                            const float* __restrict__ as3, const float* __restrict__ ad3,
                            int* __restrict__ cursor, int n) {
    int i = blockIdx.x * blockDim.x + threadIdx.x;
    if (i < n) { cursor[i] = 0; return; }
    i -= n;
    if (i < 128 * 256) {
        int k = i >> 8, c = i & 255;
        W1T[(size_t)c * 128 + k] = f2bf(W1[i]);
        return;
    }
    i -= 128 * 256;
    if (i < 256 * 256) {
        int k = i >> 8, c = i & 255;
        W2T[(size_t)c * 256 + k] = f2bf(W2[i]);
        return;
    }
    i -= 256 * 256;
    if (i < 256 * 40) {
        int k = i / 40, c = i - k * 40;
        W3T[(size_t)c * 256 + k] = f2bf(W3[i]);
        return;
    }
    i -= 256 * 40;
    if (i < 1024) {
        int h = i >> 7, k = i & 127;
        float acc = 0.f;
#pragma unroll
        for (int c = 0; c < 32; ++c) acc += W1[k * 256 + h * 32 + c] * as1[h * 32 + c];
        W1T[(size_t)(256 + h) * 128 + k] = f2bf(acc);
        return;
    }
    i -= 1024;
    if (i < 1024) {
        int h = i >> 7, k = i & 127;
        float acc = 0.f;
#pragma unroll
        for (int c = 0; c < 32; ++c) acc += W1[k * 256 + h * 32 + c] * ad1[h * 32 + c];
        W1T[(size_t)(264 + h) * 128 + k] = f2bf(acc);
        return;
    }
    i -= 1024;
    if (i < 2048) {
        int h = i >> 8, k = i & 255;
        float acc = 0.f;
#pragma unroll
        for (int c = 0; c < 32; ++c) acc += W2[k * 256 + h * 32 + c] * as2[h * 32 + c];
        W2T[(size_t)(256 + h) * 256 + k] = f2bf(acc);
        return;
    }
    i -= 2048;
    if (i < 2048) {
        int h = i >> 8, k = i & 255;
        float acc = 0.f;
#pragma unroll
        for (int c = 0; c < 32; ++c) acc += W2[k * 256 + h * 32 + c] * ad2[h * 32 + c];
        W2T[(size_t)(264 + h) * 256 + k] = f2bf(acc);
        return;
    }
    i -= 2048;
    if (i < 256) {
        float acc = 0.f;
#pragma unroll
        for (int c = 0; c < 40; ++c) acc += W3[i * 40 + c] * as3[c];
        W3T[(size_t)40 * 256 + i] = f2bf(acc);
        return;
    }
    i -= 256;
    if (i < 256) {
        float acc = 0.f;
#pragma unroll
        for (int c = 0; c < 40; ++c) acc += W3[i * 40 + c] * ad3[c];
        W3T[(size_t)41 * 256 + i] = f2bf(acc);
        return;
    }
}

// ---------------- MFMA GEMM bodies ------------------------------------------

DEV_INLINE int lds_slot(int r, int c) { return r * 4 + ((c + (r >> 1)) & 3); }

// generic bf16-A GEMM; feature cols -> fp8 (C8); al cols -> f32
DEV_INLINE void gemm_body(ushort_t* __restrict__ As, ushort_t* __restrict__ Bs,
                          const ushort_t* __restrict__ A, const ushort_t* __restrict__ BT,
                          uchar_t* __restrict__ C8,
                          float* __restrict__ ALS, float* __restrict__ ALD,
                          int M, int NOUT, int NH, int NTOT, int K, int bx, int by) {
    const int tid = threadIdx.x;
    const int wave = tid >> 6, lane = tid & 63;
    const int row0 = by * 64;
    const int col0 = bx * 64;

    const int sr = tid >> 2, sc = tid & 3;
    const int a_row = row0 + sr;
    const int b_row = col0 + sr;

    const int fr = lane & 15;
    const int fc = lane >> 4;

    f32x4 acc0 = {}, acc1 = {}, acc2 = {}, acc3 = {};

    for (int k0 = 0; k0 < K; k0 += 32) {
        short8 av = {}, bv = {};
        if (a_row < M) av = *(const short8*)(A + (size_t)a_row * K + k0 + sc * 8);
        if (b_row < NTOT) bv = *(const short8*)(BT + (size_t)b_row * K + k0 + sc * 8);
        __syncthreads();
        *(short8*)(As + lds_slot(sr, sc) * 8) = av;
        *(short8*)(Bs + lds_slot(sr, sc) * 8) = bv;
        __syncthreads();

        const int arow = wave * 16 + fr;
        short8 afrag = *(const short8*)(As + lds_slot(arow, fc) * 8);
        short8 b0 = *(const short8*)(Bs + lds_slot(0 * 16 + fr, fc) * 8);
        short8 b1 = *(const short8*)(Bs + lds_slot(1 * 16 + fr, fc) * 8);
        short8 b2 = *(const short8*)(Bs + lds_slot(2 * 16 + fr, fc) * 8);
        short8 b3 = *(const short8*)(Bs + lds_slot(3 * 16 + fr, fc) * 8);
        acc0 = __builtin_amdgcn_mfma_f32_16x16x32_bf16(afrag, b0, acc0, 0, 0, 0);
        acc1 = __builtin_amdgcn_mfma_f32_16x16x32_bf16(afrag, b1, acc1, 0, 0, 0);
        acc2 = __builtin_amdgcn_mfma_f32_16x16x32_bf16(afrag, b2, acc2, 0, 0, 0);
        acc3 = __builtin_amdgcn_mfma_f32_16x16x32_bf16(afrag, b3, acc3, 0, 0, 0);
    }
    __syncthreads();

    const int crow = row0 + wave * 16 + (lane >> 4) * 4;
    const int ccol = col0 + (lane & 15);
    f32x4 accs[4] = {acc0, acc1, acc2, acc3};
#pragma unroll
    for (int ct = 0; ct < 4; ++ct) {
        int col = ccol + ct * 16;
#pragma unroll
        for (int j = 0; j < 4; ++j) {
            int row = crow + j;
            if (row >= M) continue;
            float v = accs[ct][j];
            if (col < NOUT) {
                C8[(size_t)row * NOUT + col] = (uchar_t)f2fp8(v);
            } else {
                int cc = col - NOUT;
                if (cc < NH) ALS[(size_t)row * NH + cc] = v;
                else if (cc < 2 * NH) ALD[(size_t)row * NH + (cc - NH)] = v;
            }
        }
    }
}

// layer-1 GEMM: A staged directly from f32 x (register cast), K=128, fp8 out
DEV_INLINE void gemm1_body(ushort_t* __restrict__ As, ushort_t* __restrict__ Bs,
                           const float* __restrict__ X, const ushort_t* __restrict__ BT,
                           uchar_t* __restrict__ C8, float* __restrict__ ALS,
                           float* __restrict__ ALD, int M, int bx, int by) {
    const int tid = threadIdx.x;
    const int wave = tid >> 6, lane = tid & 63;
    const int row0 = by * 64;
    const int col0 = bx * 64;

    const int sr = tid >> 2, sc = tid & 3;
    const int a_row = row0 + sr;
    const int b_row = col0 + sr;

    const int fr = lane & 15;
    const int fc = lane >> 4;

    f32x4 acc0 = {}, acc1 = {}, acc2 = {}, acc3 = {};

    for (int k0 = 0; k0 < 128; k0 += 32) {
        short8 av = {}, bv = {};
        if (a_row < M) {
            const float* xp = X + (size_t)a_row * 128 + k0 + sc * 8;
            float4 f0 = *(const float4*)(xp);
            float4 f1 = *(const float4*)(xp + 4);
            av[0] = (short)f2bf(f0.x); av[1] = (short)f2bf(f0.y);
            av[2] = (short)f2bf(f0.z); av[3] = (short)f2bf(f0.w);
            av[4] = (short)f2bf(f1.x); av[5] = (short)f2bf(f1.y);
            av[6] = (short)f2bf(f1.z); av[7] = (short)f2bf(f1.w);
        }
        if (b_row < 272) bv = *(const short8*)(BT + (size_t)b_row * 128 + k0 + sc * 8);
        __syncthreads();
        *(short8*)(As + lds_slot(sr, sc) * 8) = av;
        *(short8*)(Bs + lds_slot(sr, sc) * 8) = bv;
        __syncthreads();

        const int arow = wave * 16 + fr;
        short8 afrag = *(const short8*)(As + lds_slot(arow, fc) * 8);
        short8 b0 = *(const short8*)(Bs + lds_slot(0 * 16 + fr, fc) * 8);
        short8 b1 = *(const short8*)(Bs + lds_slot(1 * 16 + fr, fc) * 8);
        short8 b2 = *(const short8*)(Bs + lds_slot(2 * 16 + fr, fc) * 8);
        short8 b3 = *(const short8*)(Bs + lds_slot(3 * 16 + fr, fc) * 8);
        acc0 = __builtin_amdgcn_mfma_f32_16x16x32_bf16(afrag, b0, acc0, 0, 0, 0);
        acc1 = __builtin_amdgcn_mfma_f32_16x16x32_bf16(afrag, b1, acc1, 0, 0, 0);
        acc2 = __builtin_amdgcn_mfma_f32_16x16x32_bf16(afrag, b2, acc2, 0, 0, 0);
        acc3 = __builtin_amdgcn_mfma_f32_16x16x32_bf16(afrag, b3, acc3, 0, 0, 0);
    }
    __syncthreads();

    const int crow = row0 + wave * 16 + (lane >> 4) * 4;
    const int ccol = col0 + (lane & 15);
    f32x4 accs[4] = {acc0, acc1, acc2, acc3};
#pragma unroll
    for (int ct = 0; ct < 4; ++ct) {
        int col = ccol + ct * 16;
#pragma unroll
        for (int j = 0; j < 4; ++j) {
            int row = crow + j;
            if (row >= M) continue;
            float v = accs[ct][j];
            if (col < 256) {
                C8[(size_t)row * 256 + col] = (uchar_t)f2fp8(v);
            } else {
                int cc = col - 256;
                if (cc < 8) ALS[(size_t)row * 8 + cc] = v;
                else if (cc < 16) ALD[(size_t)row * 8 + (cc - 8)] = v;
            }
        }
    }
}

__global__ __launch_bounds__(256) void gemm_kernel(const ushort_t* __restrict__ A,
                                                   const ushort_t* __restrict__ BT,
                                                   uchar_t* __restrict__ C8,
                                                   float* __restrict__ ALS,
                                                   float* __restrict__ ALD,
                                                   int M, int NOUT, int NH, int NTOT,
                                                   int K, int gx) {
    __shared__ ushort_t As[64 * 32];
    __shared__ ushort_t Bs[64 * 32];
    gemm_body(As, Bs, A, BT, C8, ALS, ALD, M, NOUT, NH, NTOT, K,
              blockIdx.x % gx, blockIdx.x / gx);
}

// blocks [0, svb): ELL scatter (1 edge/thread); blocks [svb, ..): layer-1 GEMM
__global__ __launch_bounds__(256) void scatter_gemm1_kernel(const int* __restrict__ src,
                                                            const int* __restrict__ dst,
                                                            int* __restrict__ cursor,
                                                            int* __restrict__ ell, int e,
                                                            int svb,
                                                            const float* __restrict__ X,
                                                            const ushort_t* __restrict__ BT,
                                                            uchar_t* __restrict__ C8,
                                                            float* __restrict__ ALS,
                                                            float* __restrict__ ALD,
                                                            int M, int gx) {
    __shared__ ushort_t As[64 * 32];
    __shared__ ushort_t Bs[64 * 32];
    if (blockIdx.x < svb) {
        int i = blockIdx.x * 256 + threadIdx.x;
        if (i < e) {
            int d = dst[i];
            int p = atomicAdd(&cursor[d], 1);
            ell[d * ELLW + p] = src[i];
        }
        return;
    }
    int b = blockIdx.x - svb;
    gemm1_body(As, Bs, X, BT, C8, ALS, ALD, M, b % gx, b / gx);
}

// ---------------- aggregation, layers 1-2 (fp8 gathers) ----------------------
// FUSE3=0: write h (bf16) for next GEMM.  FUSE3=1: compute layer-3 columns
// (40 features -> xp3 bf16, + als3/ald3 f32) directly from f32 h in registers.

template <int FUSE3>
__global__ __launch_bounds__(256) void aggregate_h8_kernel(const uchar_t* __restrict__ xp8,
                                                           const float* __restrict__ als,
                                                           const float* __restrict__ ald,
                                                           const int* __restrict__ degv,
                                                           const int* __restrict__ ell,
                                                           const float* __restrict__ bias,
                                                           ushort_t* __restrict__ out,
                                                           const ushort_t* __restrict__ W3T,
                                                           ushort_t* __restrict__ xp3,
                                                           float* __restrict__ als3,
                                                           float* __restrict__ ald3,
                                                           int n) {
    int node = (blockIdx.x * blockDim.x + threadIdx.x) >> 6;
    int lane = threadIdx.x & 63;
    if (node >= n) return;
    const int half = lane >> 5;
    const int lh = lane & 31;
    const int ch = lh * 8;                 // 8 channels (bytes) per lane
    const int head = lh >> 2;
    const int deg = degv[node];
    const int rs = node * ELLW, re = rs + deg;
    const float ad = ald[node * 8 + head];
    const float m = leaky02(als[node * 8 + head] + ad);   // shift = self-loop logit

    float acc[8];
    float ssum;
    if (half == 0) {                       // self loop counted once
        uint2 sv = *(const uint2*)(xp8 + (size_t)node * 256 + ch);
        float sf[8];
        fp8x8_dec(sv, sf);
#pragma unroll
        for (int i = 0; i < 8; ++i) acc[i] = sf[i];
        ssum = 1.0f;
    } else {
#pragma unroll
        for (int i = 0; i < 8; ++i) acc[i] = 0.f;
        ssum = 0.f;
    }

    for (int base = rs; base < re; base += 64) {
        const int cnt = (re - base < 64) ? (re - base) : 64;
        int myi = (lane < cnt) ? ell[base + lane] : 0;
        int j = 0;
        for (; j + 8 <= cnt; j += 8) {     // 8 edges: 4 per half, 4 loads in flight
            int s0 = __shfl(myi, j + half);
            int s1 = __shfl(myi, j + 2 + half);
            int s2 = __shfl(myi, j + 4 + half);
            int s3 = __shfl(myi, j + 6 + half);
            float a0 = als[s0 * 8 + head];
            float a1 = als[s1 * 8 + head];
            float a2 = als[s2 * 8 + head];
            float a3 = als[s3 * 8 + head];
            uint2 v0 = *(const uint2*)(xp8 + (size_t)s0 * 256 + ch);
            uint2 v1 = *(const uint2*)(xp8 + (size_t)s1 * 256 + ch);
            uint2 v2 = *(const uint2*)(xp8 + (size_t)s2 * 256 + ch);
            uint2 v3 = *(const uint2*)(xp8 + (size_t)s3 * 256 + ch);
            float p0 = __expf(leaky02(a0 + ad) - m);
            float p1 = __expf(leaky02(a1 + ad) - m);
            float p2 = __expf(leaky02(a2 + ad) - m);
            float p3 = __expf(leaky02(a3 + ad) - m);
            ssum += (p0 + p1) + (p2 + p3);
            float f0[8], f1[8], f2[8], f3[8];
            fp8x8_dec(v0, f0);
            fp8x8_dec(v1, f1);
            fp8x8_dec(v2, f2);
            fp8x8_dec(v3, f3);
#pragma unroll
            for (int i = 0; i < 8; ++i)
                acc[i] += (p0 * f0[i] + p1 * f1[i]) + (p2 * f2[i] + p3 * f3[i]);
        }
        for (; j < cnt; j += 2) {          // guarded tail
            int jj = j + half;
            int s = __shfl(myi, jj & 63);
            bool valid = jj < cnt;
            float a = als[s * 8 + head];
            uint2 v = *(const uint2*)(xp8 + (size_t)s * 256 + ch);
            float p = valid ? __expf(leaky02(a + ad) - m) : 0.f;
            ssum += p;
            float fv[8];
            fp8x8_dec(v, fv);
#pragma unroll
            for (int i = 0; i < 8; ++i) acc[i] += p * fv[i];
        }
    }

    ssum += __shfl_xor(ssum, 32);
#pragma unroll
    for (int i = 0; i < 8; ++i) acc[i] += __shfl_xor(acc[i], 32);

    if (FUSE3 == 0) {
        if (half == 0) {
            float inv = 1.f / ssum;
            float4 ba = *(const float4*)(bias + ch);
            float4 bb = *(const float4*)(bias + ch + 4);
            float bv[8] = {ba.x, ba.y, ba.z, ba.w, bb.x, bb.y, bb.z, bb.w};
            short8 o;
#pragma unroll
            for (int i = 0; i < 8; ++i) o[i] = (short)f2bf(elu1(acc[i] * inv + bv[i]));
            *(short8*)(out + (size_t)node * 256 + ch) = o;
        }
    } else {
        // both halves hold combined acc/ssum -> compute h in f32 registers
        float inv = 1.f / ssum;
        float4 ba = *(const float4*)(bias + ch);
        float4 bb = *(const float4*)(bias + ch + 4);
        float bv[8] = {ba.x, ba.y, ba.z, ba.w, bb.x, bb.y, bb.z, bb.w};
        float hf[8];
#pragma unroll
        for (int i = 0; i < 8; ++i) hf[i] = elu1(acc[i] * inv + bv[i]);

        // layer-3: 42 output columns, 21 per half; butterfly-reduce per column
        float res = 0.f;
#pragma unroll
        for (int idx = 0; idx < 21; ++idx) {
            int c = half * 21 + idx;
            short8 w = *(const short8*)(W3T + (size_t)c * 256 + ch);
            float p = hf[0] * bf2f((ushort_t)w[0]) + hf[1] * bf2f((ushort_t)w[1])
                    + hf[2] * bf2f((ushort_t)w[2]) + hf[3] * bf2f((ushort_t)w[3])
                    + hf[4] * bf2f((ushort_t)w[4]) + hf[5] * bf2f((ushort_t)w[5])
                    + hf[6] * bf2f((ushort_t)w[6]) + hf[7] * bf2f((ushort_t)w[7]);
            p += __shfl_xor(p, 1);
            p += __shfl_xor(p, 2);
            p += __shfl_xor(p, 4);
            p += __shfl_xor(p, 8);
            p += __shfl_xor(p, 16);
            if (lh == idx) res = p;
        }
        if (lh < 21) {
            int c = half * 21 + lh;
            if (c < 40)      xp3[(size_t)node * 40 + c] = f2bf(res);
            else if (c == 40) als3[node] = res;
            else             ald3[node] = res;
        }
    }
}

// ---------------- aggregation layer 3 (H=1, C=40, bf16) + log_softmax --------

__global__ __launch_bounds__(256) void aggregate_out_kernel(const ushort_t* __restrict__ xp,
                                                            const float* __restrict__ als,
                                                            const float* __restrict__ ald,
                                                            const int* __restrict__ degv,
                                                            const int* __restrict__ ell,
                                                            const float* __restrict__ bias,
                                                            float* __restrict__ out, int n) {
    int node = (blockIdx.x * blockDim.x + threadIdx.x) >> 6;
    int lane = threadIdx.x & 63;
    if (node >= n) return;
    const int half = lane >> 5;
    const int lh = lane & 31;
    const bool act = lh < 20;
    const int ch = lh * 2;
    const int deg = degv[node];
    const int rs = node * ELLW, re = rs + deg;
    const float ad = ald[node];
    const float m = leaky02(als[node] + ad);

    float a0, a1, ssum;
    if (half == 0) {
        if (act) {
            ushort2 sv = *(const ushort2*)(xp + (size_t)node * 40 + ch);
            a0 = bf2f(sv.x); a1 = bf2f(sv.y);
        } else { a0 = a1 = 0.f; }
        ssum = 1.0f;
    } else { a0 = a1 = 0.f; ssum = 0.f; }

    for (int base = rs; base < re; base += 64) {
        const int cnt = (re - base < 64) ? (re - base) : 64;
        int myi = (lane < cnt) ? ell[base + lane] : 0;
        int j = 0;
        for (; j + 8 <= cnt; j += 8) {
            int s0 = __shfl(myi, j + half);
            int s1 = __shfl(myi, j + 2 + half);
            int s2 = __shfl(myi, j + 4 + half);
            int s3 = __shfl(myi, j + 6 + half);
            float e0 = als[s0];
            float e1 = als[s1];
            float e2 = als[s2];
            float e3 = als[s3];
            ushort2 v0 = act ? *(const ushort2*)(xp + (size_t)s0 * 40 + ch) : ushort2{0, 0};
            ushort2 v1 = act ? *(const ushort2*)(xp + (size_t)s1 * 40 + ch) : ushort2{0, 0};
            ushort2 v2 = act ? *(const ushort2*)(xp + (size_t)s2 * 40 + ch) : ushort2{0, 0};
            ushort2 v3 = act ? *(const ushort2*)(xp + (size_t)s3 * 40 + ch) : ushort2{0, 0};
            float p0 = __expf(leaky02(e0 + ad) - m);
            float p1 = __expf(leaky02(e1 + ad) - m);
            float p2 = __expf(leaky02(e2 + ad) - m);
            float p3 = __expf(leaky02(e3 + ad) - m);
            ssum += (p0 + p1) + (p2 + p3);
            a0 += (p0 * bf2f(v0.x) + p1 * bf2f(v1.x)) + (p2 * bf2f(v2.x) + p3 * bf2f(v3.x));
            a1 += (p0 * bf2f(v0.y) + p1 * bf2f(v1.y)) + (p2 * bf2f(v2.y) + p3 * bf2f(v3.y));
        }
        for (; j < cnt; j += 2) {
            int jj = j + half;
            int s = __shfl(myi, jj & 63);
            bool valid = jj < cnt;
            float a = als[s];
            ushort2 v = act ? *(const ushort2*)(xp + (size_t)s * 40 + ch) : ushort2{0, 0};
            float p = valid ? __expf(leaky02(a + ad) - m) : 0.f;
            ssum += p;
            a0 += p * bf2f(v.x);
            a1 += p * bf2f(v.y);
        }
    }

    ssum += __shfl_xor(ssum, 32);
    a0 += __shfl_xor(a0, 32);
    a1 += __shfl_xor(a1, 32);

    float inv = 1.f / ssum;
    float2 b2 = act ? *(const float2*)(bias + ch) : float2{0.f, 0.f};
    float o0 = act ? (a0 * inv + b2.x) : -INFINITY;
    float o1 = act ? (a1 * inv + b2.y) : -INFINITY;

    float mx = fmaxf(o0, o1);
#pragma unroll
    for (int off = 16; off >= 1; off >>= 1) mx = fmaxf(mx, __shfl_xor(mx, off));
    float ex = act ? (__expf(o0 - mx) + __expf(o1 - mx)) : 0.f;
#pragma unroll
    for (int off = 16; off >= 1; off >>= 1) ex += __shfl_xor(ex, off);
    float lse = mx + __logf(ex);
    if (half == 0 && act) {
        float2 o = {o0 - lse, o1 - lse};
        *(float2*)(out + (size_t)node * 40 + ch) = o;
    }
}

// ---------------------------------------------------------------------------

extern "C" void kernel_launch(void* const* d_in, const int* in_sizes, int n_in,
                              void* d_out, int out_size, void* d_ws, size_t ws_size,
                              hipStream_t stream) {
    const float* x      = (const float*)d_in[0];
    const int*   edge   = (const int*)d_in[1];
    const float* W1     = (const float*)d_in[2];
    const float* a_src1 = (const float*)d_in[3];
    const float* a_dst1 = (const float*)d_in[4];
    const float* b1     = (const float*)d_in[5];
    const float* W2     = (const float*)d_in[6];
    const float* a_src2 = (const float*)d_in[7];
    const float* a_dst2 = (const float*)d_in[8];
    const float* b2     = (const float*)d_in[9];
    const float* W3     = (const float*)d_in[10];
    const float* a_src3 = (const float*)d_in[11];
    const float* a_dst3 = (const float*)d_in[12];
    const float* b3     = (const float*)d_in[13];
    float* out = (float*)d_out;

    const int n = in_sizes[0] / 128;   // 10000
    const int e = in_sizes[1] / 2;     // 320000

    char* ws = (char*)d_ws;
    size_t off = 0;
    auto alloc = [&](size_t bytes) -> void* {
        void* p = ws + off;
        off += (bytes + 255) & ~(size_t)255;
        return p;
    };
    uchar_t*  xp8       = (uchar_t*)alloc((size_t)n * 256);       // fp8 features (L1/L2)
    ushort_t* h_bf      = (ushort_t*)alloc((size_t)n * 256 * 2);  // agg1 output (GEMM2 A)
    ushort_t* xp3       = (ushort_t*)alloc((size_t)n * 40 * 2);   // L3 features bf16
    ushort_t* W1T       = (ushort_t*)alloc((size_t)272 * 128 * 2);
    ushort_t* W2T       = (ushort_t*)alloc((size_t)272 * 256 * 2);
    ushort_t* W3T       = (ushort_t*)alloc((size_t)42 * 256 * 2);
    float*    als       = (float*)alloc((size_t)n * 8 * 4);
    float*    ald       = (float*)alloc((size_t)n * 8 * 4);
    float*    als3      = (float*)alloc((size_t)n * 4);
    float*    ald3      = (float*)alloc((size_t)n * 4);
    int*      cursor    = (int*)alloc((size_t)n * 4);
    int*      ell       = (int*)alloc((size_t)n * ELLW * 4);
    (void)ws_size;

    const int* srcs = edge;
    const int* dsts = edge + e;

    const int mby = (n + 63) / 64;             // 157
    const int svb = (e + 255) / 256;           // scatter blocks (1 edge/thread)

    // K1: prep (cursor zero + W transposes + al folds)
    {
        int prep_total = n + 128 * 256 + 256 * 256 + 256 * 40
                       + 1024 + 1024 + 2048 + 2048 + 256 + 256;
        prep_kernel<<<(prep_total + 255) / 256, 256, 0, stream>>>(
            W1, W1T, W2, W2T, W3, W3T,
            a_src1, a_dst1, a_src2, a_dst2, a_src3, a_dst3, cursor, n);
    }
    // K2: ELL scatter || layer-1 GEMM (fp8 out)
    scatter_gemm1_kernel<<<svb + 5 * mby, 256, 0, stream>>>(
        srcs, dsts, cursor, ell, e, svb, x, W1T, xp8, als, ald, n, 5);

    const int agg_grid = (n * 64 + 255) / 256;

    // K3: layer-1 aggregation (+bias+ELU) -> h_bf
    aggregate_h8_kernel<0><<<agg_grid, 256, 0, stream>>>(
        xp8, als, ald, cursor, ell, b1, h_bf, nullptr, nullptr, nullptr, nullptr, n);
    // K4: layer-2 GEMM (fp8 out + al fold)
    gemm_kernel<<<5 * mby, 256, 0, stream>>>(h_bf, W2T, xp8, als, ald,
                                             n, 256, 8, 272, 256, 5);
    // K5: layer-2 aggregation + fused layer-3 GEMM -> xp3, als3, ald3
    aggregate_h8_kernel<1><<<agg_grid, 256, 0, stream>>>(
        xp8, als, ald, cursor, ell, b2, nullptr, W3T, xp3, als3, ald3, n);
    // K6: layer-3 aggregation + bias + log_softmax
    aggregate_out_kernel<<<agg_grid, 256, 0, stream>>>(xp3, als3, ald3, cursor, ell, b3, out, n);
}